// Round 4
// baseline (299.869 us; speedup 1.0000x reference)
//
#include <hip/hip_runtime.h>
#include <math.h>

#define PB 9                    // 512 nodes per partition bin
#define PW (1 << PB)
#define BCAP 10240              // bin capacity: lambda=8192, +22 sigma
#define CHUNK 8192              // edges per partition chunk (R4: halved, 2x blocks)
#define HBITS 15                // deg_out hist range: 32768 nodes packed u16 (64KB LDS)
#define WORDS (1 << (HBITS - 1))
#define HS 64                   // deg_out edge slices (R4: doubled, full-GPU hist)
#define BSTRIDE 16              // bin_cur padding: one counter per 64B line

typedef __attribute__((ext_vector_type(8))) short short8;
typedef __attribute__((ext_vector_type(4))) float floatx4;

// ---------------- helpers: bf16 pack/unpack (RNE) ----------------

__device__ __forceinline__ float bflo(unsigned u) { return __builtin_bit_cast(float, u << 16); }
__device__ __forceinline__ float bfhi(unsigned u) { return __builtin_bit_cast(float, u & 0xffff0000u); }
__device__ __forceinline__ unsigned short f2bf(float f) {
    unsigned u = __builtin_bit_cast(unsigned, f);
    u += 0x7fffu + ((u >> 16) & 1u);
    return (unsigned short)(u >> 16);
}
__device__ __forceinline__ void fma8(uint4 p, float d, float* a) {
    a[0] += d * bflo(p.x); a[1] += d * bfhi(p.x);
    a[2] += d * bflo(p.y); a[3] += d * bfhi(p.y);
    a[4] += d * bflo(p.z); a[5] += d * bfhi(p.z);
    a[6] += d * bflo(p.w); a[7] += d * bfhi(p.w);
}
__device__ __forceinline__ void acc8(uint4 p, float* a) {
    a[0] += bflo(p.x); a[1] += bfhi(p.x);
    a[2] += bflo(p.y); a[3] += bfhi(p.y);
    a[4] += bflo(p.z); a[5] += bfhi(p.z);
    a[6] += bflo(p.w); a[7] += bfhi(p.w);
}
__device__ __forceinline__ uint4 pack8(const float* a) {
    uint4 r;
    r.x = (unsigned)f2bf(a[0]) | ((unsigned)f2bf(a[1]) << 16);
    r.y = (unsigned)f2bf(a[2]) | ((unsigned)f2bf(a[3]) << 16);
    r.z = (unsigned)f2bf(a[4]) | ((unsigned)f2bf(a[5]) << 16);
    r.w = (unsigned)f2bf(a[6]) | ((unsigned)f2bf(a[7]) << 16);
    return r;
}
__device__ __forceinline__ float sigmoidf_(float x) { return 1.f / (1.f + __expf(-x)); }
__device__ __forceinline__ float tanhf_(float x) { return 1.f - 2.f / (1.f + __expf(2.f * x)); }

__device__ __forceinline__ short8 ldfrag_f32(const float* p) {
    float4 a = *(const float4*)p;
    float4 b = *(const float4*)(p + 4);
    short8 r;
    r[0] = (short)f2bf(a.x); r[1] = (short)f2bf(a.y);
    r[2] = (short)f2bf(a.z); r[3] = (short)f2bf(a.w);
    r[4] = (short)f2bf(b.x); r[5] = (short)f2bf(b.y);
    r[6] = (short)f2bf(b.z); r[7] = (short)f2bf(b.w);
    return r;
}

// ---------------- k_part: counting-sort one 8K-edge chunk into coarse bins ----------------
// 37KB LDS (no longer unioned with 64KB hist), 196 blocks.

__global__ __launch_bounds__(256) void k_part(
    const int* __restrict__ src, const int* __restrict__ dst, int E,
    int* __restrict__ bin_cur, unsigned* __restrict__ bins, int NBINS) {
    __shared__ int sh[CHUNK + 1024];
    int* hist = &sh[CHUNK];
    int* pref = &sh[CHUNK + 256];
    int* offs = &sh[CHUNK + 512];
    int* base = &sh[CHUNK + 768];
    int* wsc  = &sh[CHUNK + 1016];
    int tid = threadIdx.x;
    int c = blockIdx.x;
    int e0 = c * CHUNK, e1 = min(E, e0 + CHUNK);
    int n = e1 - e0, n4 = n >> 2;
    for (int b = tid; b < NBINS; b += 256) hist[b] = 0;
    __syncthreads();
    const int4* d4 = (const int4*)(dst + e0);
    const int4* s4 = (const int4*)(src + e0);
    for (int i = tid; i < n4; i += 256) {
        int4 d = d4[i];
        atomicAdd(&hist[d.x >> PB], 1);
        atomicAdd(&hist[d.y >> PB], 1);
        atomicAdd(&hist[d.z >> PB], 1);
        atomicAdd(&hist[d.w >> PB], 1);
    }
    for (int e = e0 + (n4 << 2) + tid; e < e1; e += 256) atomicAdd(&hist[dst[e] >> PB], 1);
    __syncthreads();
    // wave-parallel exclusive scan over NBINS (<=256) entries
    int hv = (tid < NBINS) ? hist[tid] : 0;
    int val = hv;
    #pragma unroll
    for (int off = 1; off < 64; off <<= 1) {
        int u = __shfl_up(val, off);
        if ((tid & 63) >= off) val += u;
    }
    if ((tid & 63) == 63) wsc[tid >> 6] = val;
    __syncthreads();
    int wb = 0;
    #pragma unroll
    for (int w = 0; w < 4; w++) if (w < (tid >> 6)) wb += wsc[w];
    if (tid < NBINS) {
        int ex = wb + val - hv;
        pref[tid] = ex;
        offs[tid] = ex;
        if (hv) base[tid] = atomicAdd(&bin_cur[tid * BSTRIDE], hv);
    }
    __syncthreads();
    for (int i = tid; i < n4; i += 256) {
        int4 d = d4[i]; int4 sv = s4[i];
        int sl;
        sl = atomicAdd(&offs[d.x >> PB], 1);
        sh[sl] = (int)(((unsigned)(d.x & (PW - 1)) << 17) | (unsigned)sv.x);
        sl = atomicAdd(&offs[d.y >> PB], 1);
        sh[sl] = (int)(((unsigned)(d.y & (PW - 1)) << 17) | (unsigned)sv.y);
        sl = atomicAdd(&offs[d.z >> PB], 1);
        sh[sl] = (int)(((unsigned)(d.z & (PW - 1)) << 17) | (unsigned)sv.z);
        sl = atomicAdd(&offs[d.w >> PB], 1);
        sh[sl] = (int)(((unsigned)(d.w & (PW - 1)) << 17) | (unsigned)sv.w);
    }
    for (int e = e0 + (n4 << 2) + tid; e < e1; e += 256) {
        int d = dst[e];
        int sl = atomicAdd(&offs[d >> PB], 1);
        sh[sl] = (int)(((unsigned)(d & (PW - 1)) << 17) | (unsigned)src[e]);
    }
    __syncthreads();
    // wave-split write-out: wave w handles bins w, w+4, ...
    int wave = tid >> 6, lane = tid & 63;
    for (int b = wave; b < NBINS; b += 4) {
        int cnt = hist[b];
        if (!cnt) continue;
        int bs = base[b], pb = pref[b];
        int lim = min(cnt, BCAP - bs);          // overflow guard (P~0)
        unsigned* outp = &bins[(size_t)b * BCAP + bs];
        for (int j = lane; j < lim; j += 64) outp[j] = (unsigned)sh[pb + j];
    }
}

// ---------------- k_hist: deg_out partial hist, u16-packed LDS, 256 blocks ----------------

__global__ __launch_bounds__(256) void k_hist(
    const int* __restrict__ src, int E,
    unsigned* __restrict__ deg_part, int NpadW, int eps) {
    __shared__ unsigned shw[WORDS];          // 64KB
    int tid = threadIdx.x;
    int hb = blockIdx.x;
    int r = hb / HS, s = hb % HS;
    int nbase = r << HBITS;
    for (int i = tid; i < WORDS; i += 256) shw[i] = 0u;
    __syncthreads();
    int e0 = s * eps, e1 = min(E, e0 + eps);
    int n = max(e1 - e0, 0), n4 = n >> 2;
    const int4* s4 = (const int4*)(src + e0);
    for (int i = tid; i < n4; i += 256) {
        int4 sv = s4[i];
        unsigned v;
        v = (unsigned)(sv.x - nbase);
        if (v < (unsigned)(1 << HBITS)) atomicAdd(&shw[v >> 1], 1u << ((v & 1) << 4));
        v = (unsigned)(sv.y - nbase);
        if (v < (unsigned)(1 << HBITS)) atomicAdd(&shw[v >> 1], 1u << ((v & 1) << 4));
        v = (unsigned)(sv.z - nbase);
        if (v < (unsigned)(1 << HBITS)) atomicAdd(&shw[v >> 1], 1u << ((v & 1) << 4));
        v = (unsigned)(sv.w - nbase);
        if (v < (unsigned)(1 << HBITS)) atomicAdd(&shw[v >> 1], 1u << ((v & 1) << 4));
    }
    for (int e = e0 + (n4 << 2) + tid; e < e1; e += 256) {
        unsigned v = (unsigned)(src[e] - nbase);
        if (v < (unsigned)(1 << HBITS)) atomicAdd(&shw[v >> 1], 1u << ((v & 1) << 4));
    }
    __syncthreads();
    unsigned* dp = deg_part + (size_t)s * NpadW + (nbase >> 1);
    for (int i = tid; i < WORDS; i += 256) dp[i] = shw[i];
}

// ---------------- k_gemm1: xw1 = [x|h]@Wg, UNSCALED (dno folded into agg1) ----------------
// Standalone: 32KB LDS -> 5 blocks/CU, grid 1024.

__global__ __launch_bounds__(256) void k_gemm1(
    const float* __restrict__ x, const float* __restrict__ h, const float* __restrict__ Wg,
    unsigned short* __restrict__ xw1, int N) {
    constexpr int NT = 8;                    // NOUT = 128
    __shared__ short Wswz[128 * 128];        // 32KB: [ks][nt][lane][8] bf16
    int tid = threadIdx.x;
    for (int idx = tid; idx < 128 * 128; idx += 256) {
        int j = idx & 7, l = (idx >> 3) & 63, rest = idx >> 9;
        int nt = rest % NT, ks = rest / NT;
        int k = ks * 32 + ((l >> 4) << 3) + j;
        int n = nt * 16 + (l & 15);
        Wswz[idx] = (short)f2bf(Wg[k * 128 + n]);
    }
    __syncthreads();
    int wave = tid >> 6, lane = tid & 63;
    int ml = lane & 15, quad = lane >> 4;
    for (int mb = blockIdx.x * 64; mb < N; mb += gridDim.x * 64) {
        int row = mb + wave * 16 + ml;
        int rc = row < N ? row : N - 1;
        floatx4 acc[NT];
        #pragma unroll
        for (int nt = 0; nt < NT; nt++) acc[nt] = (floatx4){0.f, 0.f, 0.f, 0.f};
        #pragma unroll
        for (int ks = 0; ks < 4; ks++) {
            const float* basep = (ks < 2) ? x : h;
            int ko = (ks & 1) * 32 + quad * 8;
            short8 a = ldfrag_f32(&basep[(size_t)rc * 64 + ko]);
            #pragma unroll
            for (int nt = 0; nt < NT; nt++) {
                short8 b = *(const short8*)&Wswz[((ks * NT + nt) * 64 + lane) * 8];
                acc[nt] = __builtin_amdgcn_mfma_f32_16x16x32_bf16(a, b, acc[nt], 0, 0, 0);
            }
        }
        int r0 = mb + wave * 16 + quad * 4;
        #pragma unroll
        for (int nt = 0; nt < NT; nt++) {
            #pragma unroll
            for (int i = 0; i < 4; i++) {
                int gr = r0 + i;
                if (gr < N) xw1[(size_t)gr * 128 + nt * 16 + ml] = f2bf(acc[nt][i]);
            }
        }
    }
}

// ---------------- k_csr: fine CSR per bin (LDS sort, int4 I/O, shfl scan) || dno norm ----

__global__ __launch_bounds__(256) void k_csr(
    unsigned* __restrict__ bins, const int* __restrict__ bin_cur,
    const unsigned* __restrict__ deg_part, int* __restrict__ row_beg, int* __restrict__ deg_in,
    float* __restrict__ dni, float* __restrict__ dno, int N, int NpadW, int NBINS) {
    int tid = threadIdx.x;
    int bid = blockIdx.x;
    if (bid >= NBINS) {
        int i = (bid - NBINS) * 256 + tid;
        if (i < N) {
            int w = i >> 1, shf = (i & 1) << 4;
            int acc = 0;
            #pragma unroll 8
            for (int s = 0; s < HS; s++) acc += (int)((deg_part[(size_t)s * NpadW + w] >> shf) & 0xffffu);
            dno[i] = rsqrtf(fmaxf((float)acc, 1.0f));
        }
        return;
    }
    __shared__ int eidx_s[BCAP];
    __shared__ int fh[PW], fp[PW], offs[PW];
    __shared__ int wsc2[4];
    int b = bid;
    int cnt = min(bin_cur[b * BSTRIDE], BCAP);
    unsigned* bp = &bins[(size_t)b * BCAP];
    int n4 = cnt >> 2;
    const uint4* bp4 = (const uint4*)bp;
    for (int i = tid; i < PW; i += 256) fh[i] = 0;
    __syncthreads();
    for (int i = tid; i < n4; i += 256) {
        uint4 v = bp4[i];
        atomicAdd(&fh[v.x >> 17], 1);
        atomicAdd(&fh[v.y >> 17], 1);
        atomicAdd(&fh[v.z >> 17], 1);
        atomicAdd(&fh[v.w >> 17], 1);
    }
    for (int j = (n4 << 2) + tid; j < cnt; j += 256) atomicAdd(&fh[bp[j] >> 17], 1);
    __syncthreads();
    // wave-parallel exclusive scan over PW=512 entries (2 per thread)
    {
        int a0 = fh[2 * tid], a1 = fh[2 * tid + 1];
        int ps = a0 + a1;
        int val = ps;
        #pragma unroll
        for (int off = 1; off < 64; off <<= 1) {
            int u = __shfl_up(val, off);
            if ((tid & 63) >= off) val += u;
        }
        if ((tid & 63) == 63) wsc2[tid >> 6] = val;
        __syncthreads();
        int wb = 0;
        #pragma unroll
        for (int w = 0; w < 4; w++) if (w < (tid >> 6)) wb += wsc2[w];
        int ex = wb + val - ps;
        fp[2 * tid] = ex; fp[2 * tid + 1] = ex + a0;
        offs[2 * tid] = ex; offs[2 * tid + 1] = ex + a0;
    }
    __syncthreads();
    for (int i = tid; i < n4; i += 256) {
        uint4 v = bp4[i];
        int sl;
        sl = atomicAdd(&offs[v.x >> 17], 1); eidx_s[sl] = (int)(v.x & 0x1FFFFu);
        sl = atomicAdd(&offs[v.y >> 17], 1); eidx_s[sl] = (int)(v.y & 0x1FFFFu);
        sl = atomicAdd(&offs[v.z >> 17], 1); eidx_s[sl] = (int)(v.z & 0x1FFFFu);
        sl = atomicAdd(&offs[v.w >> 17], 1); eidx_s[sl] = (int)(v.w & 0x1FFFFu);
    }
    for (int j = (n4 << 2) + tid; j < cnt; j += 256) {
        unsigned v = bp[j];
        int sl = atomicAdd(&offs[v >> 17], 1);
        eidx_s[sl] = (int)(v & 0x1FFFFu);
    }
    __syncthreads();
    uint4* bpw = (uint4*)bp;
    for (int i = tid; i < n4; i += 256) {
        uint4 o;
        o.x = (unsigned)eidx_s[4 * i];     o.y = (unsigned)eidx_s[4 * i + 1];
        o.z = (unsigned)eidx_s[4 * i + 2]; o.w = (unsigned)eidx_s[4 * i + 3];
        bpw[i] = o;
    }
    for (int j = (n4 << 2) + tid; j < cnt; j += 256) bp[j] = (unsigned)eidx_s[j];
    int nb = b << PB;
    for (int i = tid; i < PW; i += 256) {
        int node = nb + i;
        if (node < N) {
            row_beg[node] = b * BCAP + fp[i];
            int dg = fh[i];
            deg_in[node] = dg;
            dni[node] = rsqrtf(fmaxf((float)dg, 1.0f));
        }
    }
}

// ---------------- gemm2: xw2[n] = dno[n] * ([x[n] fp32, rhb[n] bf16] @ Wc) ----------------

__global__ __launch_bounds__(256) void k_gemm2(
    const float* __restrict__ x, const unsigned short* __restrict__ rhb,
    const float* __restrict__ Wc, const float* __restrict__ dno,
    unsigned short* __restrict__ xw2, int N) {
    constexpr int NT = 4;           // NOUT = 64
    __shared__ short Wswz[4 * NT * 64 * 8];  // 16 KB
    int tid = threadIdx.x;
    for (int idx = tid; idx < 128 * 64; idx += 256) {
        int j = idx & 7, l = (idx >> 3) & 63, rest = idx >> 9;
        int nt = rest % NT, ks = rest / NT;
        int k = ks * 32 + ((l >> 4) << 3) + j;
        int n = nt * 16 + (l & 15);
        Wswz[idx] = (short)f2bf(Wc[k * 64 + n]);
    }
    __syncthreads();
    int wave = tid >> 6, lane = tid & 63;
    int ml = lane & 15, quad = lane >> 4;
    for (int mb = blockIdx.x * 64; mb < N; mb += gridDim.x * 64) {
        int row = mb + wave * 16 + ml;
        int rc = row < N ? row : N - 1;
        floatx4 acc[NT];
        #pragma unroll
        for (int nt = 0; nt < NT; nt++) acc[nt] = (floatx4){0.f, 0.f, 0.f, 0.f};
        #pragma unroll
        for (int ks = 0; ks < 4; ks++) {
            int ko = (ks & 1) * 32 + quad * 8;
            short8 a;
            if (ks < 2) a = ldfrag_f32(&x[(size_t)rc * 64 + ko]);
            else        a = *(const short8*)&rhb[(size_t)rc * 64 + ko];
            #pragma unroll
            for (int nt = 0; nt < NT; nt++) {
                short8 b = *(const short8*)&Wswz[((ks * NT + nt) * 64 + lane) * 8];
                acc[nt] = __builtin_amdgcn_mfma_f32_16x16x32_bf16(a, b, acc[nt], 0, 0, 0);
            }
        }
        int r0 = mb + wave * 16 + quad * 4;
        float sv[4];
        #pragma unroll
        for (int i = 0; i < 4; i++) sv[i] = dno[min(r0 + i, N - 1)];
        #pragma unroll
        for (int nt = 0; nt < NT; nt++) {
            #pragma unroll
            for (int i = 0; i < 4; i++) {
                int gr = r0 + i;
                if (gr < N) xw2[(size_t)gr * 64 + nt * 16 + ml] = f2bf(acc[nt][i] * sv[i]);
            }
        }
    }
}

// ---------------- agg1 (fused gates): 16 lanes/node, bf16 gather, per-edge dno fma ----------
// R4: back to unroll-4 (R2 config) — unroll-8 was neutral (fabric ceiling), lower VGPR.

__global__ __launch_bounds__(256) void k_agg1(
    const unsigned short* __restrict__ xw1, const int* __restrict__ row_beg,
    const int* __restrict__ deg_in, const unsigned* __restrict__ srt,
    const float* __restrict__ dno, const float* __restrict__ dni,
    const float* __restrict__ bg, const float* __restrict__ h,
    float* __restrict__ ug, unsigned short* __restrict__ rh, int N) {
    int tx = threadIdx.x & 15;
    int ty = threadIdx.x >> 4;  // 16 nodes per block
    for (int v = blockIdx.x * 16 + ty; v < N; v += gridDim.x * 16) {
        int beg = row_beg[v];
        int end = beg + deg_in[v];
        float a[8] = {};
        int e = beg;
        for (; e + 3 < end; e += 4) {
            int s0 = srt[e], s1 = srt[e + 1], s2 = srt[e + 2], s3 = srt[e + 3];
            float d0 = dno[s0], d1 = dno[s1], d2 = dno[s2], d3 = dno[s3];
            uint4 p0 = *(const uint4*)&xw1[(size_t)s0 * 128 + tx * 8];
            uint4 p1 = *(const uint4*)&xw1[(size_t)s1 * 128 + tx * 8];
            uint4 p2 = *(const uint4*)&xw1[(size_t)s2 * 128 + tx * 8];
            uint4 p3 = *(const uint4*)&xw1[(size_t)s3 * 128 + tx * 8];
            fma8(p0, d0, a); fma8(p1, d1, a); fma8(p2, d2, a); fma8(p3, d3, a);
        }
        for (; e < end; e++) {
            int s = srt[e];
            float d = dno[s];
            uint4 p = *(const uint4*)&xw1[(size_t)s * 128 + tx * 8];
            fma8(p, d, a);
        }
        float sc = dni[v];
        float4 b0 = *(const float4*)&bg[tx * 8];
        float4 b1 = *(const float4*)&bg[tx * 8 + 4];
        float g[8];
        g[0] = sigmoidf_(a[0] * sc + b0.x); g[1] = sigmoidf_(a[1] * sc + b0.y);
        g[2] = sigmoidf_(a[2] * sc + b0.z); g[3] = sigmoidf_(a[3] * sc + b0.w);
        g[4] = sigmoidf_(a[4] * sc + b1.x); g[5] = sigmoidf_(a[5] * sc + b1.y);
        g[6] = sigmoidf_(a[6] * sc + b1.z); g[7] = sigmoidf_(a[7] * sc + b1.w);
        if (tx < 8) {  // reset gate cols tx*8..+7 -> rh = r*h (bf16)
            float4 h0 = *(const float4*)&h[(size_t)v * 64 + tx * 8];
            float4 h1 = *(const float4*)&h[(size_t)v * 64 + tx * 8 + 4];
            float r[8] = {g[0] * h0.x, g[1] * h0.y, g[2] * h0.z, g[3] * h0.w,
                          g[4] * h1.x, g[5] * h1.y, g[6] * h1.z, g[7] * h1.w};
            *(uint4*)&rh[(size_t)v * 64 + tx * 8] = pack8(r);
        } else {       // update gate -> ug (fp32)
            int c = (tx - 8) * 8;
            float4 o0 = {g[0], g[1], g[2], g[3]};
            float4 o1 = {g[4], g[5], g[6], g[7]};
            *(float4*)&ug[(size_t)v * 64 + c] = o0;
            *(float4*)&ug[(size_t)v * 64 + c + 4] = o1;
        }
    }
}

// ---------------- agg2 (fused GRU blend): 8 lanes/node, bf16 gather ----------------

__global__ __launch_bounds__(256) void k_agg2(
    const unsigned short* __restrict__ xw2, const int* __restrict__ row_beg,
    const int* __restrict__ deg_in, const unsigned* __restrict__ srt,
    const float* __restrict__ dni, const float* __restrict__ bc,
    const float* __restrict__ h, const float* __restrict__ ug, float* __restrict__ out, int N) {
    int tx = threadIdx.x & 7;
    int ty = threadIdx.x >> 3;  // 32 nodes per block
    for (int v = blockIdx.x * 32 + ty; v < N; v += gridDim.x * 32) {
        int beg = row_beg[v];
        int end = beg + deg_in[v];
        float a[8] = {};
        int e = beg;
        for (; e + 3 < end; e += 4) {
            int s0 = srt[e], s1 = srt[e + 1], s2 = srt[e + 2], s3 = srt[e + 3];
            uint4 p0 = *(const uint4*)&xw2[(size_t)s0 * 64 + tx * 8];
            uint4 p1 = *(const uint4*)&xw2[(size_t)s1 * 64 + tx * 8];
            uint4 p2 = *(const uint4*)&xw2[(size_t)s2 * 64 + tx * 8];
            uint4 p3 = *(const uint4*)&xw2[(size_t)s3 * 64 + tx * 8];
            acc8(p0, a); acc8(p1, a); acc8(p2, a); acc8(p3, a);
        }
        for (; e < end; e++) {
            int s = srt[e];
            uint4 p = *(const uint4*)&xw2[(size_t)s * 64 + tx * 8];
            acc8(p, a);
        }
        float sc = dni[v];
        float4 b0 = *(const float4*)&bc[tx * 8];
        float4 b1 = *(const float4*)&bc[tx * 8 + 4];
        float c[8];
        c[0] = tanhf_(a[0] * sc + b0.x); c[1] = tanhf_(a[1] * sc + b0.y);
        c[2] = tanhf_(a[2] * sc + b0.z); c[3] = tanhf_(a[3] * sc + b0.w);
        c[4] = tanhf_(a[4] * sc + b1.x); c[5] = tanhf_(a[5] * sc + b1.y);
        c[6] = tanhf_(a[6] * sc + b1.z); c[7] = tanhf_(a[7] * sc + b1.w);
        float4 u0 = *(const float4*)&ug[(size_t)v * 64 + tx * 8];
        float4 u1 = *(const float4*)&ug[(size_t)v * 64 + tx * 8 + 4];
        float4 h0 = *(const float4*)&h[(size_t)v * 64 + tx * 8];
        float4 h1 = *(const float4*)&h[(size_t)v * 64 + tx * 8 + 4];
        float4 o0 = {u0.x * h0.x + (1.f - u0.x) * c[0], u0.y * h0.y + (1.f - u0.y) * c[1],
                     u0.z * h0.z + (1.f - u0.z) * c[2], u0.w * h0.w + (1.f - u0.w) * c[3]};
        float4 o1 = {u1.x * h1.x + (1.f - u1.x) * c[4], u1.y * h1.y + (1.f - u1.y) * c[5],
                     u1.z * h1.z + (1.f - u1.z) * c[6], u1.w * h1.w + (1.f - u1.w) * c[7]};
        *(float4*)&out[(size_t)v * 64 + tx * 8] = o0;
        *(float4*)&out[(size_t)v * 64 + tx * 8 + 4] = o1;
    }
}

// ---------------- launch ----------------

extern "C" void kernel_launch(void* const* d_in, const int* in_sizes, int n_in,
                              void* d_out, int out_size, void* d_ws, size_t ws_size,
                              hipStream_t stream) {
    const float* x  = (const float*)d_in[0];
    const float* h  = (const float*)d_in[1];
    const int*   src = (const int*)d_in[2];
    const int*   dst = (const int*)d_in[3];
    const float* Wg = (const float*)d_in[4];
    const float* bg = (const float*)d_in[5];
    const float* Wc = (const float*)d_in[6];
    const float* bc = (const float*)d_in[7];
    float* out = (float*)d_out;

    const int N = in_sizes[0] / 64;
    const int E = in_sizes[2];
    const int NBINS = (N + PW - 1) >> PB;          // coarse bins (512 nodes)
    const int NCH = (E + CHUNK - 1) / CHUNK;       // partition chunks
    const int NR = (N + (1 << HBITS) - 1) >> HBITS; // deg_out hist node ranges (32768 each)
    const int NpadW = NR << (HBITS - 1);           // words per slice
    const int NH = NR * HS;                        // hist blocks
    const int eps = (((E + HS - 1) / HS) + 3) & ~3; // slice size, 4-aligned for int4

    char* ws = (char*)d_ws;
    size_t off = 0;
    auto alloc = [&](size_t bytes) -> char* {
        char* p = ws + off;
        off = (off + bytes + 255) & ~(size_t)255;
        return p;
    };
    int* bin_cur = (int*)alloc((size_t)NBINS * BSTRIDE * 4);   // padded: 1 counter / 64B
    int* row_beg = (int*)alloc((size_t)N * 4);
    int* deg_in  = (int*)alloc((size_t)N * 4);
    float* dno = (float*)alloc((size_t)N * 4);
    float* dni = (float*)alloc((size_t)N * 4);
    unsigned* bins = (unsigned*)alloc((size_t)NBINS * BCAP * 4);
    unsigned short* rhb = (unsigned short*)alloc((size_t)N * 64 * 2);
    unsigned short* xw1 = (unsigned short*)alloc((size_t)N * 128 * 2);
    float* ug = (float*)alloc((size_t)N * 64 * 4);
    unsigned short* xw2 = xw1;          // xw1 dead after agg1; reuse
    unsigned* deg_part = (unsigned*)ug; // HS*NpadW*4 = 16.8MB <= ug's 25.6MB;
                                        // dead before agg1 writes ug

    hipMemsetAsync(bin_cur, 0, (size_t)NBINS * BSTRIDE * 4, stream);
    k_part<<<NCH, 256, 0, stream>>>(src, dst, E, bin_cur, bins, NBINS);
    k_hist<<<NH, 256, 0, stream>>>(src, E, deg_part, NpadW, eps);
    k_gemm1<<<1024, 256, 0, stream>>>(x, h, Wg, xw1, N);
    k_csr<<<NBINS + (N + 255) / 256, 256, 0, stream>>>(bins, bin_cur, deg_part,
                                                       row_beg, deg_in, dni, dno,
                                                       N, NpadW, NBINS);
    k_agg1<<<(N + 15) / 16, 256, 0, stream>>>(xw1, row_beg, deg_in, bins,
                                              dno, dni, bg, h, ug, rhb, N);
    k_gemm2<<<512, 256, 0, stream>>>(x, rhb, Wc, dno, xw2, N);
    k_agg2<<<(N + 31) / 32, 256, 0, stream>>>(xw2, row_beg, deg_in, bins,
                                              dni, bc, h, ug, out, N);
}

// Round 6
// 279.871 us; speedup vs baseline: 1.0715x; 1.0715x over previous
//
#include <hip/hip_runtime.h>
#include <math.h>

#define PB 9                    // 512 nodes per partition bin
#define PW (1 << PB)
#define BCAP 10240              // bin capacity: lambda=8192, +22 sigma
#define CHUNK 16384             // edges per partition chunk (R2 value: fused roles overlap)
#define HBITS 15                // deg_out hist range: 32768 nodes packed u16 (64KB LDS)
#define WORDS (1 << (HBITS - 1))
#define HS 32                   // deg_out edge slices (R2 value)
#define BSTRIDE 16              // bin_cur padding: one counter per 64B line

typedef __attribute__((ext_vector_type(8))) short short8;
typedef __attribute__((ext_vector_type(4))) float floatx4;

// ---------------- helpers: bf16 pack/unpack (RNE) ----------------

__device__ __forceinline__ float bflo(unsigned u) { return __builtin_bit_cast(float, u << 16); }
__device__ __forceinline__ float bfhi(unsigned u) { return __builtin_bit_cast(float, u & 0xffff0000u); }
__device__ __forceinline__ unsigned short f2bf(float f) {
    unsigned u = __builtin_bit_cast(unsigned, f);
    u += 0x7fffu + ((u >> 16) & 1u);
    return (unsigned short)(u >> 16);
}
__device__ __forceinline__ void fma8(uint4 p, float d, float* a) {
    a[0] += d * bflo(p.x); a[1] += d * bfhi(p.x);
    a[2] += d * bflo(p.y); a[3] += d * bfhi(p.y);
    a[4] += d * bflo(p.z); a[5] += d * bfhi(p.z);
    a[6] += d * bflo(p.w); a[7] += d * bfhi(p.w);
}
__device__ __forceinline__ void acc8(uint4 p, float* a) {
    a[0] += bflo(p.x); a[1] += bfhi(p.x);
    a[2] += bflo(p.y); a[3] += bfhi(p.y);
    a[4] += bflo(p.z); a[5] += bfhi(p.z);
    a[6] += bflo(p.w); a[7] += bfhi(p.w);
}
__device__ __forceinline__ uint4 pack8(const float* a) {
    uint4 r;
    r.x = (unsigned)f2bf(a[0]) | ((unsigned)f2bf(a[1]) << 16);
    r.y = (unsigned)f2bf(a[2]) | ((unsigned)f2bf(a[3]) << 16);
    r.z = (unsigned)f2bf(a[4]) | ((unsigned)f2bf(a[5]) << 16);
    r.w = (unsigned)f2bf(a[6]) | ((unsigned)f2bf(a[7]) << 16);
    return r;
}
__device__ __forceinline__ float sigmoidf_(float x) { return 1.f / (1.f + __expf(-x)); }
__device__ __forceinline__ float tanhf_(float x) { return 1.f - 2.f / (1.f + __expf(2.f * x)); }

__device__ __forceinline__ short8 ldfrag_f32(const float* p) {
    float4 a = *(const float4*)p;
    float4 b = *(const float4*)(p + 4);
    short8 r;
    r[0] = (short)f2bf(a.x); r[1] = (short)f2bf(a.y);
    r[2] = (short)f2bf(a.z); r[3] = (short)f2bf(a.w);
    r[4] = (short)f2bf(b.x); r[5] = (short)f2bf(b.y);
    r[6] = (short)f2bf(b.z); r[7] = (short)f2bf(b.w);
    return r;
}

// ---------------- fused: gemm1 (MFMA) || deg_out hist (LDS, packed u16) || partition ----
// Roles by blockIdx: [0,Gg)=gemm1; [Gg,Gg+NH)=deg_out hist; rest=partition chunks.
// NOTE (R4 lesson): same-stream dispatches serialize; this block-role fusion IS the
// overlap mechanism for the build phase. Do not split.

__global__ __launch_bounds__(256) void k_fused(
    const float* __restrict__ x, const float* __restrict__ h, const float* __restrict__ Wg,
    const int* __restrict__ src, const int* __restrict__ dst, int E,
    int* __restrict__ bin_cur, unsigned* __restrict__ deg_part, unsigned* __restrict__ bins,
    unsigned short* __restrict__ xw1, int N, int NpadW, int NBINS, int Gg, int NH, int eps) {
    constexpr int NT = 8;                    // NOUT = 128
    __shared__ int sh[CHUNK + 1024];         // 68KB union: gemm Wswz | hist words | sort+aux
    int tid = threadIdx.x;
    int bid = blockIdx.x;
    if (bid >= Gg + NH) {
        // ---- partition role: counting-sort one chunk into coarse bins ----
        int* hist = &sh[CHUNK];
        int* pref = &sh[CHUNK + 256];
        int* offs = &sh[CHUNK + 512];
        int* base = &sh[CHUNK + 768];
        int* wsc  = &sh[CHUNK + 1016];
        int c = bid - Gg - NH;
        int e0 = c * CHUNK, e1 = min(E, e0 + CHUNK);
        int n = e1 - e0, n4 = n >> 2;
        for (int b = tid; b < NBINS; b += 256) hist[b] = 0;
        __syncthreads();
        const int4* d4 = (const int4*)(dst + e0);
        const int4* s4 = (const int4*)(src + e0);
        for (int i = tid; i < n4; i += 256) {
            int4 d = d4[i];
            atomicAdd(&hist[d.x >> PB], 1);
            atomicAdd(&hist[d.y >> PB], 1);
            atomicAdd(&hist[d.z >> PB], 1);
            atomicAdd(&hist[d.w >> PB], 1);
        }
        for (int e = e0 + (n4 << 2) + tid; e < e1; e += 256) atomicAdd(&hist[dst[e] >> PB], 1);
        __syncthreads();
        // wave-parallel exclusive scan over NBINS (<=256) entries
        int hv = (tid < NBINS) ? hist[tid] : 0;
        int val = hv;
        #pragma unroll
        for (int off = 1; off < 64; off <<= 1) {
            int u = __shfl_up(val, off);
            if ((tid & 63) >= off) val += u;
        }
        if ((tid & 63) == 63) wsc[tid >> 6] = val;
        __syncthreads();
        int wb = 0;
        #pragma unroll
        for (int w = 0; w < 4; w++) if (w < (tid >> 6)) wb += wsc[w];
        if (tid < NBINS) {
            int ex = wb + val - hv;
            pref[tid] = ex;
            offs[tid] = ex;
            if (hv) base[tid] = atomicAdd(&bin_cur[tid * BSTRIDE], hv);
        }
        __syncthreads();
        for (int i = tid; i < n4; i += 256) {
            int4 d = d4[i]; int4 sv = s4[i];
            int sl;
            sl = atomicAdd(&offs[d.x >> PB], 1);
            sh[sl] = (int)(((unsigned)(d.x & (PW - 1)) << 17) | (unsigned)sv.x);
            sl = atomicAdd(&offs[d.y >> PB], 1);
            sh[sl] = (int)(((unsigned)(d.y & (PW - 1)) << 17) | (unsigned)sv.y);
            sl = atomicAdd(&offs[d.z >> PB], 1);
            sh[sl] = (int)(((unsigned)(d.z & (PW - 1)) << 17) | (unsigned)sv.z);
            sl = atomicAdd(&offs[d.w >> PB], 1);
            sh[sl] = (int)(((unsigned)(d.w & (PW - 1)) << 17) | (unsigned)sv.w);
        }
        for (int e = e0 + (n4 << 2) + tid; e < e1; e += 256) {
            int d = dst[e];
            int sl = atomicAdd(&offs[d >> PB], 1);
            sh[sl] = (int)(((unsigned)(d & (PW - 1)) << 17) | (unsigned)src[e]);
        }
        __syncthreads();
        // wave-split write-out: wave w handles bins w, w+4, ...
        int wave = tid >> 6, lane = tid & 63;
        for (int b = wave; b < NBINS; b += 4) {
            int cnt = hist[b];
            if (!cnt) continue;
            int bs = base[b], pb = pref[b];
            int lim = min(cnt, BCAP - bs);          // overflow guard (P~0)
            unsigned* outp = &bins[(size_t)b * BCAP + bs];
            for (int j = lane; j < lim; j += 64) outp[j] = (unsigned)sh[pb + j];
        }
        return;
    }
    if (bid >= Gg) {
        // ---- deg_out hist role: node range r (32768 nodes, u16-packed), edge slice s ----
        int hb = bid - Gg;
        int r = hb / HS, s = hb % HS;
        int nbase = r << HBITS;
        unsigned* shw = (unsigned*)sh;
        for (int i = tid; i < WORDS; i += 256) shw[i] = 0u;
        __syncthreads();
        int e0 = s * eps, e1 = min(E, e0 + eps);
        int n = max(e1 - e0, 0), n4 = n >> 2;
        const int4* s4 = (const int4*)(src + e0);
        for (int i = tid; i < n4; i += 256) {
            int4 sv = s4[i];
            unsigned v;
            v = (unsigned)(sv.x - nbase);
            if (v < (unsigned)(1 << HBITS)) atomicAdd(&shw[v >> 1], 1u << ((v & 1) << 4));
            v = (unsigned)(sv.y - nbase);
            if (v < (unsigned)(1 << HBITS)) atomicAdd(&shw[v >> 1], 1u << ((v & 1) << 4));
            v = (unsigned)(sv.z - nbase);
            if (v < (unsigned)(1 << HBITS)) atomicAdd(&shw[v >> 1], 1u << ((v & 1) << 4));
            v = (unsigned)(sv.w - nbase);
            if (v < (unsigned)(1 << HBITS)) atomicAdd(&shw[v >> 1], 1u << ((v & 1) << 4));
        }
        for (int e = e0 + (n4 << 2) + tid; e < e1; e += 256) {
            unsigned v = (unsigned)(src[e] - nbase);
            if (v < (unsigned)(1 << HBITS)) atomicAdd(&shw[v >> 1], 1u << ((v & 1) << 4));
        }
        __syncthreads();
        unsigned* dp = deg_part + (size_t)s * NpadW + (nbase >> 1);
        for (int i = tid; i < WORDS; i += 256) dp[i] = shw[i];
        return;
    }
    // ---- gemm1 role: xw1 = [x|h]@Wg, UNSCALED (dno folded into agg1) ----
    short* Wswz = (short*)sh;                // [ks][nt][lane][8] bf16
    for (int idx = tid; idx < 128 * 128; idx += 256) {
        int j = idx & 7, l = (idx >> 3) & 63, rest = idx >> 9;
        int nt = rest % NT, ks = rest / NT;
        int k = ks * 32 + ((l >> 4) << 3) + j;
        int n = nt * 16 + (l & 15);
        Wswz[idx] = (short)f2bf(Wg[k * 128 + n]);
    }
    __syncthreads();
    int wave = tid >> 6, lane = tid & 63;
    int ml = lane & 15, quad = lane >> 4;
    for (int mb = bid * 64; mb < N; mb += Gg * 64) {
        int row = mb + wave * 16 + ml;
        int rc = row < N ? row : N - 1;
        floatx4 acc[NT];
        #pragma unroll
        for (int nt = 0; nt < NT; nt++) acc[nt] = (floatx4){0.f, 0.f, 0.f, 0.f};
        #pragma unroll
        for (int ks = 0; ks < 4; ks++) {
            const float* basep = (ks < 2) ? x : h;
            int ko = (ks & 1) * 32 + quad * 8;
            short8 a = ldfrag_f32(&basep[(size_t)rc * 64 + ko]);
            #pragma unroll
            for (int nt = 0; nt < NT; nt++) {
                short8 b = *(const short8*)&Wswz[((ks * NT + nt) * 64 + lane) * 8];
                acc[nt] = __builtin_amdgcn_mfma_f32_16x16x32_bf16(a, b, acc[nt], 0, 0, 0);
            }
        }
        int r0 = mb + wave * 16 + quad * 4;
        #pragma unroll
        for (int nt = 0; nt < NT; nt++) {
            #pragma unroll
            for (int i = 0; i < 4; i++) {
                int gr = r0 + i;
                if (gr < N) xw1[(size_t)gr * 128 + nt * 16 + ml] = f2bf(acc[nt][i]);
            }
        }
    }
}

// ---------------- k_csr: fine CSR per bin (LDS sort, int4 I/O, shfl scan) || dno norm ----

__global__ __launch_bounds__(256) void k_csr(
    unsigned* __restrict__ bins, const int* __restrict__ bin_cur,
    const unsigned* __restrict__ deg_part, int* __restrict__ row_beg, int* __restrict__ deg_in,
    float* __restrict__ dni, float* __restrict__ dno, int N, int NpadW, int NBINS) {
    int tid = threadIdx.x;
    int bid = blockIdx.x;
    if (bid >= NBINS) {
        int i = (bid - NBINS) * 256 + tid;
        if (i < N) {
            int w = i >> 1, shf = (i & 1) << 4;
            int acc = 0;
            #pragma unroll 8
            for (int s = 0; s < HS; s++) acc += (int)((deg_part[(size_t)s * NpadW + w] >> shf) & 0xffffu);
            dno[i] = rsqrtf(fmaxf((float)acc, 1.0f));
        }
        return;
    }
    __shared__ int eidx_s[BCAP];
    __shared__ int fh[PW], fp[PW], offs[PW];
    __shared__ int wsc2[4];
    int b = bid;
    int cnt = min(bin_cur[b * BSTRIDE], BCAP);
    unsigned* bp = &bins[(size_t)b * BCAP];
    int n4 = cnt >> 2;
    const uint4* bp4 = (const uint4*)bp;
    for (int i = tid; i < PW; i += 256) fh[i] = 0;
    __syncthreads();
    for (int i = tid; i < n4; i += 256) {
        uint4 v = bp4[i];
        atomicAdd(&fh[v.x >> 17], 1);
        atomicAdd(&fh[v.y >> 17], 1);
        atomicAdd(&fh[v.z >> 17], 1);
        atomicAdd(&fh[v.w >> 17], 1);
    }
    for (int j = (n4 << 2) + tid; j < cnt; j += 256) atomicAdd(&fh[bp[j] >> 17], 1);
    __syncthreads();
    // wave-parallel exclusive scan over PW=512 entries (2 per thread)
    {
        int a0 = fh[2 * tid], a1 = fh[2 * tid + 1];
        int ps = a0 + a1;
        int val = ps;
        #pragma unroll
        for (int off = 1; off < 64; off <<= 1) {
            int u = __shfl_up(val, off);
            if ((tid & 63) >= off) val += u;
        }
        if ((tid & 63) == 63) wsc2[tid >> 6] = val;
        __syncthreads();
        int wb = 0;
        #pragma unroll
        for (int w = 0; w < 4; w++) if (w < (tid >> 6)) wb += wsc2[w];
        int ex = wb + val - ps;
        fp[2 * tid] = ex; fp[2 * tid + 1] = ex + a0;
        offs[2 * tid] = ex; offs[2 * tid + 1] = ex + a0;
    }
    __syncthreads();
    for (int i = tid; i < n4; i += 256) {
        uint4 v = bp4[i];
        int sl;
        sl = atomicAdd(&offs[v.x >> 17], 1); eidx_s[sl] = (int)(v.x & 0x1FFFFu);
        sl = atomicAdd(&offs[v.y >> 17], 1); eidx_s[sl] = (int)(v.y & 0x1FFFFu);
        sl = atomicAdd(&offs[v.z >> 17], 1); eidx_s[sl] = (int)(v.z & 0x1FFFFu);
        sl = atomicAdd(&offs[v.w >> 17], 1); eidx_s[sl] = (int)(v.w & 0x1FFFFu);
    }
    for (int j = (n4 << 2) + tid; j < cnt; j += 256) {
        unsigned v = bp[j];
        int sl = atomicAdd(&offs[v >> 17], 1);
        eidx_s[sl] = (int)(v & 0x1FFFFu);
    }
    __syncthreads();
    uint4* bpw = (uint4*)bp;
    for (int i = tid; i < n4; i += 256) {
        uint4 o;
        o.x = (unsigned)eidx_s[4 * i];     o.y = (unsigned)eidx_s[4 * i + 1];
        o.z = (unsigned)eidx_s[4 * i + 2]; o.w = (unsigned)eidx_s[4 * i + 3];
        bpw[i] = o;
    }
    for (int j = (n4 << 2) + tid; j < cnt; j += 256) bp[j] = (unsigned)eidx_s[j];
    int nb = b << PB;
    for (int i = tid; i < PW; i += 256) {
        int node = nb + i;
        if (node < N) {
            row_beg[node] = b * BCAP + fp[i];
            int dg = fh[i];
            deg_in[node] = dg;
            dni[node] = rsqrtf(fmaxf((float)dg, 1.0f));
        }
    }
}

// ---------------- agg1 (fused gates + gemm2): 16 lanes/node, bf16 gather ----------------
// R5: gemm2 fused into the epilogue. After gates: stage cat2=[x|r*h] bf16 in LDS,
// Wc swizzled in LDS (staged at block start, overlaps the gather), then 4 MFMA/wave
// compute xw2 = dno*(cat2@Wc) directly. Removes k_gemm2 + rhb round-trip + x re-read.
// One block = exactly 16 nodes (no grid-stride: barrier must be uniform).

__global__ __launch_bounds__(256) void k_agg1(
    const unsigned short* __restrict__ xw1, const int* __restrict__ row_beg,
    const int* __restrict__ deg_in, const unsigned* __restrict__ srt,
    const float* __restrict__ dno, const float* __restrict__ dni,
    const float* __restrict__ bg, const float* __restrict__ h,
    const float* __restrict__ x, const float* __restrict__ Wc,
    float* __restrict__ ug, unsigned short* __restrict__ xw2, int N) {
    __shared__ short Wswz[4 * 4 * 64 * 8];          // 16 KB: [ks][nt][lane][8] bf16
    __shared__ __align__(16) short cat2s[16 * 128]; // 4 KB: [node][k] bf16
    int tid = threadIdx.x;
    // stage Wc swizzled (same fragment layout as old k_gemm2; barrier below covers it)
    for (int idx = tid; idx < 128 * 64; idx += 256) {
        int j = idx & 7, l = (idx >> 3) & 63, rest = idx >> 9;
        int nt = rest & 3, ks = rest >> 2;
        int k = ks * 32 + ((l >> 4) << 3) + j;
        int n = nt * 16 + (l & 15);
        Wswz[idx] = (short)f2bf(Wc[k * 64 + n]);
    }
    int tx = tid & 15;
    int ty = tid >> 4;  // 16 nodes per block
    int vbase = blockIdx.x * 16;
    int v = vbase + ty;
    int vc = min(v, N - 1);
    int beg = row_beg[vc];
    int end = beg + deg_in[vc];
    float a[8] = {};
    int e = beg;
    for (; e + 3 < end; e += 4) {
        int s0 = srt[e], s1 = srt[e + 1], s2 = srt[e + 2], s3 = srt[e + 3];
        float d0 = dno[s0], d1 = dno[s1], d2 = dno[s2], d3 = dno[s3];
        uint4 p0 = *(const uint4*)&xw1[(size_t)s0 * 128 + tx * 8];
        uint4 p1 = *(const uint4*)&xw1[(size_t)s1 * 128 + tx * 8];
        uint4 p2 = *(const uint4*)&xw1[(size_t)s2 * 128 + tx * 8];
        uint4 p3 = *(const uint4*)&xw1[(size_t)s3 * 128 + tx * 8];
        fma8(p0, d0, a); fma8(p1, d1, a); fma8(p2, d2, a); fma8(p3, d3, a);
    }
    for (; e < end; e++) {
        int s = srt[e];
        float d = dno[s];
        uint4 p = *(const uint4*)&xw1[(size_t)s * 128 + tx * 8];
        fma8(p, d, a);
    }
    float sc = dni[vc];
    float4 b0 = *(const float4*)&bg[tx * 8];
    float4 b1 = *(const float4*)&bg[tx * 8 + 4];
    float g[8];
    g[0] = sigmoidf_(a[0] * sc + b0.x); g[1] = sigmoidf_(a[1] * sc + b0.y);
    g[2] = sigmoidf_(a[2] * sc + b0.z); g[3] = sigmoidf_(a[3] * sc + b0.w);
    g[4] = sigmoidf_(a[4] * sc + b1.x); g[5] = sigmoidf_(a[5] * sc + b1.y);
    g[6] = sigmoidf_(a[6] * sc + b1.z); g[7] = sigmoidf_(a[7] * sc + b1.w);
    if (tx < 8) {  // reset gate cols tx*8..+7 -> cat2[64 + tx*8 ..] = r*h (bf16, LDS)
        float4 h0 = *(const float4*)&h[(size_t)vc * 64 + tx * 8];
        float4 h1 = *(const float4*)&h[(size_t)vc * 64 + tx * 8 + 4];
        float r[8] = {g[0] * h0.x, g[1] * h0.y, g[2] * h0.z, g[3] * h0.w,
                      g[4] * h1.x, g[5] * h1.y, g[6] * h1.z, g[7] * h1.w};
        *(uint4*)&cat2s[ty * 128 + 64 + tx * 8] = pack8(r);
    } else {       // update gate -> ug (fp32, global); also stage x chunk into cat2
        int c = (tx - 8) * 8;
        if (v < N) {
            float4 o0 = {g[0], g[1], g[2], g[3]};
            float4 o1 = {g[4], g[5], g[6], g[7]};
            *(float4*)&ug[(size_t)v * 64 + c] = o0;
            *(float4*)&ug[(size_t)v * 64 + c + 4] = o1;
        }
        float4 x0 = *(const float4*)&x[(size_t)vc * 64 + c];
        float4 x1 = *(const float4*)&x[(size_t)vc * 64 + c + 4];
        float xx[8] = {x0.x, x0.y, x0.z, x0.w, x1.x, x1.y, x1.z, x1.w};
        *(uint4*)&cat2s[ty * 128 + c] = pack8(xx);
    }
    __syncthreads();
    // ---- fused gemm2 epilogue: wave w computes col-tile nt=w of xw2 for the 16 nodes ----
    int wave = tid >> 6, lane = tid & 63;
    int ml = lane & 15, quad = lane >> 4;
    floatx4 acc2 = (floatx4){0.f, 0.f, 0.f, 0.f};
    #pragma unroll
    for (int ks = 0; ks < 4; ks++) {
        short8 af = *(const short8*)&cat2s[ml * 128 + ks * 32 + quad * 8];
        short8 bf = *(const short8*)&Wswz[((ks * 4 + wave) * 64 + lane) * 8];
        acc2 = __builtin_amdgcn_mfma_f32_16x16x32_bf16(af, bf, acc2, 0, 0, 0);
    }
    int c = wave * 16 + ml;
    #pragma unroll
    for (int i = 0; i < 4; i++) {
        int v2 = vbase + quad * 4 + i;
        if (v2 < N) xw2[(size_t)v2 * 64 + c] = f2bf(acc2[i] * dno[v2]);
    }
}

// ---------------- agg2 (fused GRU blend): 8 lanes/node, bf16 gather ----------------

__global__ __launch_bounds__(256) void k_agg2(
    const unsigned short* __restrict__ xw2, const int* __restrict__ row_beg,
    const int* __restrict__ deg_in, const unsigned* __restrict__ srt,
    const float* __restrict__ dni, const float* __restrict__ bc,
    const float* __restrict__ h, const float* __restrict__ ug, float* __restrict__ out, int N) {
    int tx = threadIdx.x & 7;
    int ty = threadIdx.x >> 3;  // 32 nodes per block
    for (int v = blockIdx.x * 32 + ty; v < N; v += gridDim.x * 32) {
        int beg = row_beg[v];
        int end = beg + deg_in[v];
        float a[8] = {};
        int e = beg;
        for (; e + 3 < end; e += 4) {
            int s0 = srt[e], s1 = srt[e + 1], s2 = srt[e + 2], s3 = srt[e + 3];
            uint4 p0 = *(const uint4*)&xw2[(size_t)s0 * 64 + tx * 8];
            uint4 p1 = *(const uint4*)&xw2[(size_t)s1 * 64 + tx * 8];
            uint4 p2 = *(const uint4*)&xw2[(size_t)s2 * 64 + tx * 8];
            uint4 p3 = *(const uint4*)&xw2[(size_t)s3 * 64 + tx * 8];
            acc8(p0, a); acc8(p1, a); acc8(p2, a); acc8(p3, a);
        }
        for (; e < end; e++) {
            int s = srt[e];
            uint4 p = *(const uint4*)&xw2[(size_t)s * 64 + tx * 8];
            acc8(p, a);
        }
        float sc = dni[v];
        float4 b0 = *(const float4*)&bc[tx * 8];
        float4 b1 = *(const float4*)&bc[tx * 8 + 4];
        float c[8];
        c[0] = tanhf_(a[0] * sc + b0.x); c[1] = tanhf_(a[1] * sc + b0.y);
        c[2] = tanhf_(a[2] * sc + b0.z); c[3] = tanhf_(a[3] * sc + b0.w);
        c[4] = tanhf_(a[4] * sc + b1.x); c[5] = tanhf_(a[5] * sc + b1.y);
        c[6] = tanhf_(a[6] * sc + b1.z); c[7] = tanhf_(a[7] * sc + b1.w);
        float4 u0 = *(const float4*)&ug[(size_t)v * 64 + tx * 8];
        float4 u1 = *(const float4*)&ug[(size_t)v * 64 + tx * 8 + 4];
        float4 h0 = *(const float4*)&h[(size_t)v * 64 + tx * 8];
        float4 h1 = *(const float4*)&h[(size_t)v * 64 + tx * 8 + 4];
        float4 o0 = {u0.x * h0.x + (1.f - u0.x) * c[0], u0.y * h0.y + (1.f - u0.y) * c[1],
                     u0.z * h0.z + (1.f - u0.z) * c[2], u0.w * h0.w + (1.f - u0.w) * c[3]};
        float4 o1 = {u1.x * h1.x + (1.f - u1.x) * c[4], u1.y * h1.y + (1.f - u1.y) * c[5],
                     u1.z * h1.z + (1.f - u1.z) * c[6], u1.w * h1.w + (1.f - u1.w) * c[7]};
        *(float4*)&out[(size_t)v * 64 + tx * 8] = o0;
        *(float4*)&out[(size_t)v * 64 + tx * 8 + 4] = o1;
    }
}

// ---------------- launch ----------------

extern "C" void kernel_launch(void* const* d_in, const int* in_sizes, int n_in,
                              void* d_out, int out_size, void* d_ws, size_t ws_size,
                              hipStream_t stream) {
    const float* x  = (const float*)d_in[0];
    const float* h  = (const float*)d_in[1];
    const int*   src = (const int*)d_in[2];
    const int*   dst = (const int*)d_in[3];
    const float* Wg = (const float*)d_in[4];
    const float* bg = (const float*)d_in[5];
    const float* Wc = (const float*)d_in[6];
    const float* bc = (const float*)d_in[7];
    float* out = (float*)d_out;

    const int N = in_sizes[0] / 64;
    const int E = in_sizes[2];
    const int NBINS = (N + PW - 1) >> PB;          // coarse bins (512 nodes)
    const int NCH = (E + CHUNK - 1) / CHUNK;       // partition chunks
    const int NR = (N + (1 << HBITS) - 1) >> HBITS; // deg_out hist node ranges (32768 each)
    const int NpadW = NR << (HBITS - 1);           // words per slice
    const int NH = NR * HS;                        // hist blocks
    const int eps = (((E + HS - 1) / HS) + 3) & ~3; // slice size, 4-aligned for int4

    char* ws = (char*)d_ws;
    size_t off = 0;
    auto alloc = [&](size_t bytes) -> char* {
        char* p = ws + off;
        off = (off + bytes + 255) & ~(size_t)255;
        return p;
    };
    int* bin_cur = (int*)alloc((size_t)NBINS * BSTRIDE * 4);   // padded: 1 counter / 64B
    int* row_beg = (int*)alloc((size_t)N * 4);
    int* deg_in  = (int*)alloc((size_t)N * 4);
    float* dno = (float*)alloc((size_t)N * 4);
    float* dni = (float*)alloc((size_t)N * 4);
    unsigned* bins = (unsigned*)alloc((size_t)NBINS * BCAP * 4);
    unsigned short* xw1 = (unsigned short*)alloc((size_t)N * 128 * 2);
    unsigned short* xw2 = (unsigned short*)alloc((size_t)N * 64 * 2);  // own buffer:
                                        // agg1 epilogue writes while other blocks gather xw1
    float* ug = (float*)alloc((size_t)N * 64 * 4);
    unsigned* deg_part = (unsigned*)ug; // HS*NpadW*4 = 8.4MB <= ug's 25.6MB;
                                        // dead before agg1 writes ug

    const int Gg = 256;                 // gemm1 blocks (dispatch first, persist)

    hipMemsetAsync(bin_cur, 0, (size_t)NBINS * BSTRIDE * 4, stream);
    k_fused<<<Gg + NH + NCH, 256, 0, stream>>>(x, h, Wg, src, dst, E,
                                               bin_cur, deg_part, bins, xw1,
                                               N, NpadW, NBINS, Gg, NH, eps);
    k_csr<<<NBINS + (N + 255) / 256, 256, 0, stream>>>(bins, bin_cur, deg_part,
                                                       row_beg, deg_in, dni, dno,
                                                       N, NpadW, NBINS);
    k_agg1<<<(N + 15) / 16, 256, 0, stream>>>(xw1, row_beg, deg_in, bins,
                                              dno, dni, bg, h, x, Wc, ug, xw2, N);
    k_agg2<<<(N + 31) / 32, 256, 0, stream>>>(xw2, row_beg, deg_in, bins,
                                              dni, bc, h, ug, out, N);
}

// Round 7
// 265.463 us; speedup vs baseline: 1.1296x; 1.0543x over previous
//
#include <hip/hip_runtime.h>
#include <math.h>

#define PB 9                    // 512 nodes per partition bin
#define PW (1 << PB)
#define BCAP 10240              // bin capacity: lambda=8192, +22 sigma
#define CHUNK 16384             // edges per partition chunk
#define HBITS 16                // deg_out hist range: 65536 nodes packed u8 (64KB LDS)
#define WORDS (1 << (HBITS - 2))
#define HS 32                   // deg_out edge slices
#define BSTRIDE 16              // bin_cur padding: one counter per 64B line

typedef __attribute__((ext_vector_type(8))) short short8;
typedef __attribute__((ext_vector_type(4))) float floatx4;

// ---------------- helpers: bf16 pack/unpack (RNE) ----------------

__device__ __forceinline__ float bflo(unsigned u) { return __builtin_bit_cast(float, u << 16); }
__device__ __forceinline__ float bfhi(unsigned u) { return __builtin_bit_cast(float, u & 0xffff0000u); }
__device__ __forceinline__ unsigned short f2bf(float f) {
    unsigned u = __builtin_bit_cast(unsigned, f);
    u += 0x7fffu + ((u >> 16) & 1u);
    return (unsigned short)(u >> 16);
}
__device__ __forceinline__ void fma8(uint4 p, float d, float* a) {
    a[0] += d * bflo(p.x); a[1] += d * bfhi(p.x);
    a[2] += d * bflo(p.y); a[3] += d * bfhi(p.y);
    a[4] += d * bflo(p.z); a[5] += d * bfhi(p.z);
    a[6] += d * bflo(p.w); a[7] += d * bfhi(p.w);
}
__device__ __forceinline__ void acc8(uint4 p, float* a) {
    a[0] += bflo(p.x); a[1] += bfhi(p.x);
    a[2] += bflo(p.y); a[3] += bfhi(p.y);
    a[4] += bflo(p.z); a[5] += bfhi(p.z);
    a[6] += bflo(p.w); a[7] += bfhi(p.w);
}
__device__ __forceinline__ uint4 pack8(const float* a) {
    uint4 r;
    r.x = (unsigned)f2bf(a[0]) | ((unsigned)f2bf(a[1]) << 16);
    r.y = (unsigned)f2bf(a[2]) | ((unsigned)f2bf(a[3]) << 16);
    r.z = (unsigned)f2bf(a[4]) | ((unsigned)f2bf(a[5]) << 16);
    r.w = (unsigned)f2bf(a[6]) | ((unsigned)f2bf(a[7]) << 16);
    return r;
}
__device__ __forceinline__ float sigmoidf_(float x) { return 1.f / (1.f + __expf(-x)); }
__device__ __forceinline__ float tanhf_(float x) { return 1.f - 2.f / (1.f + __expf(2.f * x)); }

__device__ __forceinline__ short8 ldfrag_f32(const float* p) {
    float4 a = *(const float4*)p;
    float4 b = *(const float4*)(p + 4);
    short8 r;
    r[0] = (short)f2bf(a.x); r[1] = (short)f2bf(a.y);
    r[2] = (short)f2bf(a.z); r[3] = (short)f2bf(a.w);
    r[4] = (short)f2bf(b.x); r[5] = (short)f2bf(b.y);
    r[6] = (short)f2bf(b.z); r[7] = (short)f2bf(b.w);
    return r;
}

// ---------------- fused: gemm1 (MFMA) || deg_out hist (LDS, packed u8) || partition ----
// Roles by blockIdx: [0,Gg)=gemm1; [Gg,Gg+NH)=deg_out hist; rest=partition chunks.
// NOTE (R4 lesson): same-stream dispatches serialize; this block-role fusion IS the
// overlap mechanism for the build phase. Do not split.
// NOTE (R6 lesson): no block-wide barrier after a variable-length per-thread phase
// (gather skew: E[max of 16 Poisson(16)] ~ 1.6x mean) — keep agg kernels barrier-free.
// R7: u8-packed hist (safe: max deg_out ~50 << 255) -> NR 4->2, src re-read halved,
// k_fused grid 418 blocks = fully co-resident at 2 blocks/CU.

__global__ __launch_bounds__(256) void k_fused(
    const float* __restrict__ x, const float* __restrict__ h, const float* __restrict__ Wg,
    const int* __restrict__ src, const int* __restrict__ dst, int E,
    int* __restrict__ bin_cur, unsigned* __restrict__ deg_part, unsigned* __restrict__ bins,
    unsigned short* __restrict__ xw1, int N, int NpadW, int NBINS, int Gg, int NH, int eps) {
    constexpr int NT = 8;                    // NOUT = 128
    __shared__ int sh[CHUNK + 1024];         // 68KB union: gemm Wswz | hist words | sort+aux
    int tid = threadIdx.x;
    int bid = blockIdx.x;
    if (bid >= Gg + NH) {
        // ---- partition role: counting-sort one chunk into coarse bins ----
        int* hist = &sh[CHUNK];
        int* pref = &sh[CHUNK + 256];
        int* offs = &sh[CHUNK + 512];
        int* base = &sh[CHUNK + 768];
        int* wsc  = &sh[CHUNK + 1016];
        int c = bid - Gg - NH;
        int e0 = c * CHUNK, e1 = min(E, e0 + CHUNK);
        int n = e1 - e0, n4 = n >> 2;
        for (int b = tid; b < NBINS; b += 256) hist[b] = 0;
        __syncthreads();
        const int4* d4 = (const int4*)(dst + e0);
        const int4* s4 = (const int4*)(src + e0);
        for (int i = tid; i < n4; i += 256) {
            int4 d = d4[i];
            atomicAdd(&hist[d.x >> PB], 1);
            atomicAdd(&hist[d.y >> PB], 1);
            atomicAdd(&hist[d.z >> PB], 1);
            atomicAdd(&hist[d.w >> PB], 1);
        }
        for (int e = e0 + (n4 << 2) + tid; e < e1; e += 256) atomicAdd(&hist[dst[e] >> PB], 1);
        __syncthreads();
        // wave-parallel exclusive scan over NBINS (<=256) entries
        int hv = (tid < NBINS) ? hist[tid] : 0;
        int val = hv;
        #pragma unroll
        for (int off = 1; off < 64; off <<= 1) {
            int u = __shfl_up(val, off);
            if ((tid & 63) >= off) val += u;
        }
        if ((tid & 63) == 63) wsc[tid >> 6] = val;
        __syncthreads();
        int wb = 0;
        #pragma unroll
        for (int w = 0; w < 4; w++) if (w < (tid >> 6)) wb += wsc[w];
        if (tid < NBINS) {
            int ex = wb + val - hv;
            pref[tid] = ex;
            offs[tid] = ex;
            if (hv) base[tid] = atomicAdd(&bin_cur[tid * BSTRIDE], hv);
        }
        __syncthreads();
        for (int i = tid; i < n4; i += 256) {
            int4 d = d4[i]; int4 sv = s4[i];
            int sl;
            sl = atomicAdd(&offs[d.x >> PB], 1);
            sh[sl] = (int)(((unsigned)(d.x & (PW - 1)) << 17) | (unsigned)sv.x);
            sl = atomicAdd(&offs[d.y >> PB], 1);
            sh[sl] = (int)(((unsigned)(d.y & (PW - 1)) << 17) | (unsigned)sv.y);
            sl = atomicAdd(&offs[d.z >> PB], 1);
            sh[sl] = (int)(((unsigned)(d.z & (PW - 1)) << 17) | (unsigned)sv.z);
            sl = atomicAdd(&offs[d.w >> PB], 1);
            sh[sl] = (int)(((unsigned)(d.w & (PW - 1)) << 17) | (unsigned)sv.w);
        }
        for (int e = e0 + (n4 << 2) + tid; e < e1; e += 256) {
            int d = dst[e];
            int sl = atomicAdd(&offs[d >> PB], 1);
            sh[sl] = (int)(((unsigned)(d & (PW - 1)) << 17) | (unsigned)src[e]);
        }
        __syncthreads();
        // wave-split write-out: wave w handles bins w, w+4, ...
        int wave = tid >> 6, lane = tid & 63;
        for (int b = wave; b < NBINS; b += 4) {
            int cnt = hist[b];
            if (!cnt) continue;
            int bs = base[b], pb = pref[b];
            int lim = min(cnt, BCAP - bs);          // overflow guard (P~0)
            unsigned* outp = &bins[(size_t)b * BCAP + bs];
            for (int j = lane; j < lim; j += 64) outp[j] = (unsigned)sh[pb + j];
        }
        return;
    }
    if (bid >= Gg) {
        // ---- deg_out hist role: node range r (65536 nodes, u8-packed), edge slice s ----
        int hb = bid - Gg;
        int r = hb / HS, s = hb % HS;
        int nbase = r << HBITS;
        unsigned* shw = (unsigned*)sh;
        for (int i = tid; i < WORDS; i += 256) shw[i] = 0u;
        __syncthreads();
        int e0 = s * eps, e1 = min(E, e0 + eps);
        int n = max(e1 - e0, 0), n4 = n >> 2;
        const int4* s4 = (const int4*)(src + e0);
        for (int i = tid; i < n4; i += 256) {
            int4 sv = s4[i];
            unsigned v;
            v = (unsigned)(sv.x - nbase);
            if (v < (unsigned)(1 << HBITS)) atomicAdd(&shw[v >> 2], 1u << ((v & 3) << 3));
            v = (unsigned)(sv.y - nbase);
            if (v < (unsigned)(1 << HBITS)) atomicAdd(&shw[v >> 2], 1u << ((v & 3) << 3));
            v = (unsigned)(sv.z - nbase);
            if (v < (unsigned)(1 << HBITS)) atomicAdd(&shw[v >> 2], 1u << ((v & 3) << 3));
            v = (unsigned)(sv.w - nbase);
            if (v < (unsigned)(1 << HBITS)) atomicAdd(&shw[v >> 2], 1u << ((v & 3) << 3));
        }
        for (int e = e0 + (n4 << 2) + tid; e < e1; e += 256) {
            unsigned v = (unsigned)(src[e] - nbase);
            if (v < (unsigned)(1 << HBITS)) atomicAdd(&shw[v >> 2], 1u << ((v & 3) << 3));
        }
        __syncthreads();
        unsigned* dp = deg_part + (size_t)s * NpadW + (nbase >> 2);
        for (int i = tid; i < WORDS; i += 256) dp[i] = shw[i];
        return;
    }
    // ---- gemm1 role: xw1 = [x|h]@Wg, UNSCALED (dno folded into agg1) ----
    short* Wswz = (short*)sh;                // [ks][nt][lane][8] bf16
    for (int idx = tid; idx < 128 * 128; idx += 256) {
        int j = idx & 7, l = (idx >> 3) & 63, rest = idx >> 9;
        int nt = rest % NT, ks = rest / NT;
        int k = ks * 32 + ((l >> 4) << 3) + j;
        int n = nt * 16 + (l & 15);
        Wswz[idx] = (short)f2bf(Wg[k * 128 + n]);
    }
    __syncthreads();
    int wave = tid >> 6, lane = tid & 63;
    int ml = lane & 15, quad = lane >> 4;
    for (int mb = bid * 64; mb < N; mb += Gg * 64) {
        int row = mb + wave * 16 + ml;
        int rc = row < N ? row : N - 1;
        floatx4 acc[NT];
        #pragma unroll
        for (int nt = 0; nt < NT; nt++) acc[nt] = (floatx4){0.f, 0.f, 0.f, 0.f};
        #pragma unroll
        for (int ks = 0; ks < 4; ks++) {
            const float* basep = (ks < 2) ? x : h;
            int ko = (ks & 1) * 32 + quad * 8;
            short8 a = ldfrag_f32(&basep[(size_t)rc * 64 + ko]);
            #pragma unroll
            for (int nt = 0; nt < NT; nt++) {
                short8 b = *(const short8*)&Wswz[((ks * NT + nt) * 64 + lane) * 8];
                acc[nt] = __builtin_amdgcn_mfma_f32_16x16x32_bf16(a, b, acc[nt], 0, 0, 0);
            }
        }
        int r0 = mb + wave * 16 + quad * 4;
        #pragma unroll
        for (int nt = 0; nt < NT; nt++) {
            #pragma unroll
            for (int i = 0; i < 4; i++) {
                int gr = r0 + i;
                if (gr < N) xw1[(size_t)gr * 128 + nt * 16 + ml] = f2bf(acc[nt][i]);
            }
        }
    }
}

// ---------------- k_csr: fine CSR per bin (LDS sort, int4 I/O, shfl scan) || dno norm ----

__global__ __launch_bounds__(256) void k_csr(
    unsigned* __restrict__ bins, const int* __restrict__ bin_cur,
    const unsigned* __restrict__ deg_part, int* __restrict__ row_beg, int* __restrict__ deg_in,
    float* __restrict__ dni, float* __restrict__ dno, int N, int NpadW, int NBINS) {
    int tid = threadIdx.x;
    int bid = blockIdx.x;
    if (bid >= NBINS) {
        int i = (bid - NBINS) * 256 + tid;
        if (i < N) {
            int w = i >> 2, shf = (i & 3) << 3;
            int acc = 0;
            #pragma unroll 8
            for (int s = 0; s < HS; s++) acc += (int)((deg_part[(size_t)s * NpadW + w] >> shf) & 0xffu);
            dno[i] = rsqrtf(fmaxf((float)acc, 1.0f));
        }
        return;
    }
    __shared__ int eidx_s[BCAP];
    __shared__ int fh[PW], fp[PW], offs[PW];
    __shared__ int wsc2[4];
    int b = bid;
    int cnt = min(bin_cur[b * BSTRIDE], BCAP);
    unsigned* bp = &bins[(size_t)b * BCAP];
    int n4 = cnt >> 2;
    const uint4* bp4 = (const uint4*)bp;
    for (int i = tid; i < PW; i += 256) fh[i] = 0;
    __syncthreads();
    for (int i = tid; i < n4; i += 256) {
        uint4 v = bp4[i];
        atomicAdd(&fh[v.x >> 17], 1);
        atomicAdd(&fh[v.y >> 17], 1);
        atomicAdd(&fh[v.z >> 17], 1);
        atomicAdd(&fh[v.w >> 17], 1);
    }
    for (int j = (n4 << 2) + tid; j < cnt; j += 256) atomicAdd(&fh[bp[j] >> 17], 1);
    __syncthreads();
    // wave-parallel exclusive scan over PW=512 entries (2 per thread)
    {
        int a0 = fh[2 * tid], a1 = fh[2 * tid + 1];
        int ps = a0 + a1;
        int val = ps;
        #pragma unroll
        for (int off = 1; off < 64; off <<= 1) {
            int u = __shfl_up(val, off);
            if ((tid & 63) >= off) val += u;
        }
        if ((tid & 63) == 63) wsc2[tid >> 6] = val;
        __syncthreads();
        int wb = 0;
        #pragma unroll
        for (int w = 0; w < 4; w++) if (w < (tid >> 6)) wb += wsc2[w];
        int ex = wb + val - ps;
        fp[2 * tid] = ex; fp[2 * tid + 1] = ex + a0;
        offs[2 * tid] = ex; offs[2 * tid + 1] = ex + a0;
    }
    __syncthreads();
    for (int i = tid; i < n4; i += 256) {
        uint4 v = bp4[i];
        int sl;
        sl = atomicAdd(&offs[v.x >> 17], 1); eidx_s[sl] = (int)(v.x & 0x1FFFFu);
        sl = atomicAdd(&offs[v.y >> 17], 1); eidx_s[sl] = (int)(v.y & 0x1FFFFu);
        sl = atomicAdd(&offs[v.z >> 17], 1); eidx_s[sl] = (int)(v.z & 0x1FFFFu);
        sl = atomicAdd(&offs[v.w >> 17], 1); eidx_s[sl] = (int)(v.w & 0x1FFFFu);
    }
    for (int j = (n4 << 2) + tid; j < cnt; j += 256) {
        unsigned v = bp[j];
        int sl = atomicAdd(&offs[v >> 17], 1);
        eidx_s[sl] = (int)(v & 0x1FFFFu);
    }
    __syncthreads();
    uint4* bpw = (uint4*)bp;
    for (int i = tid; i < n4; i += 256) {
        uint4 o;
        o.x = (unsigned)eidx_s[4 * i];     o.y = (unsigned)eidx_s[4 * i + 1];
        o.z = (unsigned)eidx_s[4 * i + 2]; o.w = (unsigned)eidx_s[4 * i + 3];
        bpw[i] = o;
    }
    for (int j = (n4 << 2) + tid; j < cnt; j += 256) bp[j] = (unsigned)eidx_s[j];
    int nb = b << PB;
    for (int i = tid; i < PW; i += 256) {
        int node = nb + i;
        if (node < N) {
            row_beg[node] = b * BCAP + fp[i];
            int dg = fh[i];
            deg_in[node] = dg;
            dni[node] = rsqrtf(fmaxf((float)dg, 1.0f));
        }
    }
}

// ---------------- gemm2: xw2[n] = dno[n] * ([x[n] fp32, rhb[n] bf16] @ Wc) ----------------

__global__ __launch_bounds__(256) void k_gemm2(
    const float* __restrict__ x, const unsigned short* __restrict__ rhb,
    const float* __restrict__ Wc, const float* __restrict__ dno,
    unsigned short* __restrict__ xw2, int N) {
    constexpr int NT = 4;           // NOUT = 64
    __shared__ short Wswz[4 * NT * 64 * 8];  // 16 KB
    int tid = threadIdx.x;
    for (int idx = tid; idx < 128 * 64; idx += 256) {
        int j = idx & 7, l = (idx >> 3) & 63, rest = idx >> 9;
        int nt = rest % NT, ks = rest / NT;
        int k = ks * 32 + ((l >> 4) << 3) + j;
        int n = nt * 16 + (l & 15);
        Wswz[idx] = (short)f2bf(Wc[k * 64 + n]);
    }
    __syncthreads();
    int wave = tid >> 6, lane = tid & 63;
    int ml = lane & 15, quad = lane >> 4;
    for (int mb = blockIdx.x * 64; mb < N; mb += gridDim.x * 64) {
        int row = mb + wave * 16 + ml;
        int rc = row < N ? row : N - 1;
        floatx4 acc[NT];
        #pragma unroll
        for (int nt = 0; nt < NT; nt++) acc[nt] = (floatx4){0.f, 0.f, 0.f, 0.f};
        #pragma unroll
        for (int ks = 0; ks < 4; ks++) {
            int ko = (ks & 1) * 32 + quad * 8;
            short8 a;
            if (ks < 2) a = ldfrag_f32(&x[(size_t)rc * 64 + ko]);
            else        a = *(const short8*)&rhb[(size_t)rc * 64 + ko];
            #pragma unroll
            for (int nt = 0; nt < NT; nt++) {
                short8 b = *(const short8*)&Wswz[((ks * NT + nt) * 64 + lane) * 8];
                acc[nt] = __builtin_amdgcn_mfma_f32_16x16x32_bf16(a, b, acc[nt], 0, 0, 0);
            }
        }
        int r0 = mb + wave * 16 + quad * 4;
        float sv[4];
        #pragma unroll
        for (int i = 0; i < 4; i++) sv[i] = dno[min(r0 + i, N - 1)];
        #pragma unroll
        for (int nt = 0; nt < NT; nt++) {
            #pragma unroll
            for (int i = 0; i < 4; i++) {
                int gr = r0 + i;
                if (gr < N) xw2[(size_t)gr * 64 + nt * 16 + ml] = f2bf(acc[nt][i] * sv[i]);
            }
        }
    }
}

// ---------------- agg1 (fused gates): 16 lanes/node, bf16 gather, per-edge dno fma ----------
// Barrier-free: threads retire independently (R6 lesson — no skew coupling).

__global__ __launch_bounds__(256) void k_agg1(
    const unsigned short* __restrict__ xw1, const int* __restrict__ row_beg,
    const int* __restrict__ deg_in, const unsigned* __restrict__ srt,
    const float* __restrict__ dno, const float* __restrict__ dni,
    const float* __restrict__ bg, const float* __restrict__ h,
    float* __restrict__ ug, unsigned short* __restrict__ rh, int N) {
    int tx = threadIdx.x & 15;
    int ty = threadIdx.x >> 4;  // 16 nodes per block
    for (int v = blockIdx.x * 16 + ty; v < N; v += gridDim.x * 16) {
        int beg = row_beg[v];
        int end = beg + deg_in[v];
        float a[8] = {};
        int e = beg;
        for (; e + 3 < end; e += 4) {
            int s0 = srt[e], s1 = srt[e + 1], s2 = srt[e + 2], s3 = srt[e + 3];
            float d0 = dno[s0], d1 = dno[s1], d2 = dno[s2], d3 = dno[s3];
            uint4 p0 = *(const uint4*)&xw1[(size_t)s0 * 128 + tx * 8];
            uint4 p1 = *(const uint4*)&xw1[(size_t)s1 * 128 + tx * 8];
            uint4 p2 = *(const uint4*)&xw1[(size_t)s2 * 128 + tx * 8];
            uint4 p3 = *(const uint4*)&xw1[(size_t)s3 * 128 + tx * 8];
            fma8(p0, d0, a); fma8(p1, d1, a); fma8(p2, d2, a); fma8(p3, d3, a);
        }
        for (; e < end; e++) {
            int s = srt[e];
            float d = dno[s];
            uint4 p = *(const uint4*)&xw1[(size_t)s * 128 + tx * 8];
            fma8(p, d, a);
        }
        float sc = dni[v];
        float4 b0 = *(const float4*)&bg[tx * 8];
        float4 b1 = *(const float4*)&bg[tx * 8 + 4];
        float g[8];
        g[0] = sigmoidf_(a[0] * sc + b0.x); g[1] = sigmoidf_(a[1] * sc + b0.y);
        g[2] = sigmoidf_(a[2] * sc + b0.z); g[3] = sigmoidf_(a[3] * sc + b0.w);
        g[4] = sigmoidf_(a[4] * sc + b1.x); g[5] = sigmoidf_(a[5] * sc + b1.y);
        g[6] = sigmoidf_(a[6] * sc + b1.z); g[7] = sigmoidf_(a[7] * sc + b1.w);
        if (tx < 8) {  // reset gate cols tx*8..+7 -> rh = r*h (bf16)
            float4 h0 = *(const float4*)&h[(size_t)v * 64 + tx * 8];
            float4 h1 = *(const float4*)&h[(size_t)v * 64 + tx * 8 + 4];
            float r[8] = {g[0] * h0.x, g[1] * h0.y, g[2] * h0.z, g[3] * h0.w,
                          g[4] * h1.x, g[5] * h1.y, g[6] * h1.z, g[7] * h1.w};
            *(uint4*)&rh[(size_t)v * 64 + tx * 8] = pack8(r);
        } else {       // update gate -> ug (fp32)
            int c = (tx - 8) * 8;
            float4 o0 = {g[0], g[1], g[2], g[3]};
            float4 o1 = {g[4], g[5], g[6], g[7]};
            *(float4*)&ug[(size_t)v * 64 + c] = o0;
            *(float4*)&ug[(size_t)v * 64 + c + 4] = o1;
        }
    }
}

// ---------------- agg2 (fused GRU blend): 8 lanes/node, bf16 gather ----------------

__global__ __launch_bounds__(256) void k_agg2(
    const unsigned short* __restrict__ xw2, const int* __restrict__ row_beg,
    const int* __restrict__ deg_in, const unsigned* __restrict__ srt,
    const float* __restrict__ dni, const float* __restrict__ bc,
    const float* __restrict__ h, const float* __restrict__ ug, float* __restrict__ out, int N) {
    int tx = threadIdx.x & 7;
    int ty = threadIdx.x >> 3;  // 32 nodes per block
    for (int v = blockIdx.x * 32 + ty; v < N; v += gridDim.x * 32) {
        int beg = row_beg[v];
        int end = beg + deg_in[v];
        float a[8] = {};
        int e = beg;
        for (; e + 3 < end; e += 4) {
            int s0 = srt[e], s1 = srt[e + 1], s2 = srt[e + 2], s3 = srt[e + 3];
            uint4 p0 = *(const uint4*)&xw2[(size_t)s0 * 64 + tx * 8];
            uint4 p1 = *(const uint4*)&xw2[(size_t)s1 * 64 + tx * 8];
            uint4 p2 = *(const uint4*)&xw2[(size_t)s2 * 64 + tx * 8];
            uint4 p3 = *(const uint4*)&xw2[(size_t)s3 * 64 + tx * 8];
            acc8(p0, a); acc8(p1, a); acc8(p2, a); acc8(p3, a);
        }
        for (; e < end; e++) {
            int s = srt[e];
            uint4 p = *(const uint4*)&xw2[(size_t)s * 64 + tx * 8];
            acc8(p, a);
        }
        float sc = dni[v];
        float4 b0 = *(const float4*)&bc[tx * 8];
        float4 b1 = *(const float4*)&bc[tx * 8 + 4];
        float c[8];
        c[0] = tanhf_(a[0] * sc + b0.x); c[1] = tanhf_(a[1] * sc + b0.y);
        c[2] = tanhf_(a[2] * sc + b0.z); c[3] = tanhf_(a[3] * sc + b0.w);
        c[4] = tanhf_(a[4] * sc + b1.x); c[5] = tanhf_(a[5] * sc + b1.y);
        c[6] = tanhf_(a[6] * sc + b1.z); c[7] = tanhf_(a[7] * sc + b1.w);
        float4 u0 = *(const float4*)&ug[(size_t)v * 64 + tx * 8];
        float4 u1 = *(const float4*)&ug[(size_t)v * 64 + tx * 8 + 4];
        float4 h0 = *(const float4*)&h[(size_t)v * 64 + tx * 8];
        float4 h1 = *(const float4*)&h[(size_t)v * 64 + tx * 8 + 4];
        float4 o0 = {u0.x * h0.x + (1.f - u0.x) * c[0], u0.y * h0.y + (1.f - u0.y) * c[1],
                     u0.z * h0.z + (1.f - u0.z) * c[2], u0.w * h0.w + (1.f - u0.w) * c[3]};
        float4 o1 = {u1.x * h1.x + (1.f - u1.x) * c[4], u1.y * h1.y + (1.f - u1.y) * c[5],
                     u1.z * h1.z + (1.f - u1.z) * c[6], u1.w * h1.w + (1.f - u1.w) * c[7]};
        *(float4*)&out[(size_t)v * 64 + tx * 8] = o0;
        *(float4*)&out[(size_t)v * 64 + tx * 8 + 4] = o1;
    }
}

// ---------------- launch ----------------

extern "C" void kernel_launch(void* const* d_in, const int* in_sizes, int n_in,
                              void* d_out, int out_size, void* d_ws, size_t ws_size,
                              hipStream_t stream) {
    const float* x  = (const float*)d_in[0];
    const float* h  = (const float*)d_in[1];
    const int*   src = (const int*)d_in[2];
    const int*   dst = (const int*)d_in[3];
    const float* Wg = (const float*)d_in[4];
    const float* bg = (const float*)d_in[5];
    const float* Wc = (const float*)d_in[6];
    const float* bc = (const float*)d_in[7];
    float* out = (float*)d_out;

    const int N = in_sizes[0] / 64;
    const int E = in_sizes[2];
    const int NBINS = (N + PW - 1) >> PB;          // coarse bins (512 nodes)
    const int NCH = (E + CHUNK - 1) / CHUNK;       // partition chunks
    const int NR = (N + (1 << HBITS) - 1) >> HBITS; // deg_out hist node ranges (65536 each)
    const int NpadW = NR << (HBITS - 2);           // words per slice (u8-packed)
    const int NH = NR * HS;                        // hist blocks
    const int eps = (((E + HS - 1) / HS) + 3) & ~3; // slice size, 4-aligned for int4

    char* ws = (char*)d_ws;
    size_t off = 0;
    auto alloc = [&](size_t bytes) -> char* {
        char* p = ws + off;
        off = (off + bytes + 255) & ~(size_t)255;
        return p;
    };
    int* bin_cur = (int*)alloc((size_t)NBINS * BSTRIDE * 4);   // padded: 1 counter / 64B
    int* row_beg = (int*)alloc((size_t)N * 4);
    int* deg_in  = (int*)alloc((size_t)N * 4);
    float* dno = (float*)alloc((size_t)N * 4);
    float* dni = (float*)alloc((size_t)N * 4);
    unsigned* bins = (unsigned*)alloc((size_t)NBINS * BCAP * 4);
    unsigned short* rhb = (unsigned short*)alloc((size_t)N * 64 * 2);
    unsigned short* xw1 = (unsigned short*)alloc((size_t)N * 128 * 2);
    float* ug = (float*)alloc((size_t)N * 64 * 4);
    unsigned short* xw2 = xw1;          // xw1 dead after agg1; reuse
    unsigned* deg_part = (unsigned*)ug; // HS*NpadW*4 = 4.2MB <= ug's 25.6MB;
                                        // dead before agg1 writes ug

    const int Gg = 256;                 // gemm1 blocks (dispatch first, persist)

    hipMemsetAsync(bin_cur, 0, (size_t)NBINS * BSTRIDE * 4, stream);
    k_fused<<<Gg + NH + NCH, 256, 0, stream>>>(x, h, Wg, src, dst, E,
                                               bin_cur, deg_part, bins, xw1,
                                               N, NpadW, NBINS, Gg, NH, eps);
    k_csr<<<NBINS + (N + 255) / 256, 256, 0, stream>>>(bins, bin_cur, deg_part,
                                                       row_beg, deg_in, dni, dno,
                                                       N, NpadW, NBINS);
    k_agg1<<<(N + 15) / 16, 256, 0, stream>>>(xw1, row_beg, deg_in, bins,
                                              dno, dni, bg, h, ug, rhb, N);
    k_gemm2<<<512, 256, 0, stream>>>(x, rhb, Wc, dno, xw2, N);
    k_agg2<<<(N + 31) / 32, 256, 0, stream>>>(xw2, row_beg, deg_in, bins,
                                              dni, bc, h, ug, out, N);
}

// Round 8
// 242.667 us; speedup vs baseline: 1.2357x; 1.0939x over previous
//
#include <hip/hip_runtime.h>
#include <math.h>

#define PB 9                    // 512 nodes per partition bin
#define PW (1 << PB)
#define BCAP 10240              // bin capacity: lambda=8192, +22 sigma
#define CHUNK 16384             // edges per partition chunk
#define HBITS 16                // deg_out hist range: 65536 nodes packed u8 (64KB LDS)
#define WORDS (1 << (HBITS - 2))
#define HS 32                   // deg_out edge slices
#define BSTRIDE 16              // bin_cur padding: one counter per 64B line

typedef __attribute__((ext_vector_type(8))) short short8;
typedef __attribute__((ext_vector_type(4))) float floatx4;
typedef __attribute__((ext_vector_type(2))) float floatx2;

// ---------------- helpers: bf16 pack/unpack (RNE) ----------------

__device__ __forceinline__ float bflo(unsigned u) { return __builtin_bit_cast(float, u << 16); }
__device__ __forceinline__ float bfhi(unsigned u) { return __builtin_bit_cast(float, u & 0xffff0000u); }
__device__ __forceinline__ unsigned short f2bf(float f) {
    unsigned u = __builtin_bit_cast(unsigned, f);
    u += 0x7fffu + ((u >> 16) & 1u);
    return (unsigned short)(u >> 16);
}

// ---------------- fp8 e4m3fn (OCP) encode/decode: HW cvt on gfx950, SW fallback ----------

#if __has_builtin(__builtin_amdgcn_cvt_pk_fp8_f32) && __has_builtin(__builtin_amdgcn_cvt_pk_f32_fp8)
#define FP8_HW 1
#else
#define FP8_HW 0
#endif

__device__ __forceinline__ unsigned char f8enc(float f) {
#if FP8_HW
    return (unsigned char)(__builtin_amdgcn_cvt_pk_fp8_f32(f, f, 0, false) & 0xFF);
#else
    unsigned u = __builtin_bit_cast(unsigned, f);
    unsigned s = (u >> 24) & 0x80u;
    int e = (int)((u >> 23) & 0xFF) - 127;
    unsigned m = u & 0x7FFFFFu;
    if (e >= -6) {                       // normal e4m3 range
        unsigned mant = m >> 20;
        unsigned rest = m & 0xFFFFFu;
        if (rest > 0x80000u || (rest == 0x80000u && (mant & 1))) {
            mant++;
            if (mant == 8) { mant = 0; e++; }
        }
        if (e > 8 || (e == 8 && mant > 6)) return (unsigned char)(s | 0x7E);  // clamp 448
        return (unsigned char)(s | ((unsigned)(e + 7) << 3) | mant);
    }
    float q = fabsf(f) * 512.f;          // denorm: value = round(|f|*2^9) * 2^-9
    unsigned qi = (unsigned)(q + 0.5f);
    if (qi > 7) return (unsigned char)(s | (1u << 3));
    return (unsigned char)(s | qi);
#endif
}

__device__ __forceinline__ float f8dec1(unsigned b) {
    unsigned e = (b >> 3) & 15u, m = b & 7u;
    float v = e ? __builtin_bit_cast(float, ((e + 120u) << 23) | (m << 20))
                : (float)m * 0.001953125f;
    return (b & 0x80u) ? -v : v;
}

// decode 8 fp8 (uint2) and fma into a[0..7] with scale d
__device__ __forceinline__ void fma8f8(uint2 p, float d, float* a) {
#if FP8_HW
    floatx2 v;
    v = __builtin_amdgcn_cvt_pk_f32_fp8((int)p.x, false); a[0] += d * v[0]; a[1] += d * v[1];
    v = __builtin_amdgcn_cvt_pk_f32_fp8((int)p.x, true);  a[2] += d * v[0]; a[3] += d * v[1];
    v = __builtin_amdgcn_cvt_pk_f32_fp8((int)p.y, false); a[4] += d * v[0]; a[5] += d * v[1];
    v = __builtin_amdgcn_cvt_pk_f32_fp8((int)p.y, true);  a[6] += d * v[0]; a[7] += d * v[1];
#else
    a[0] += d * f8dec1(p.x & 0xFF); a[1] += d * f8dec1((p.x >> 8) & 0xFF);
    a[2] += d * f8dec1((p.x >> 16) & 0xFF); a[3] += d * f8dec1(p.x >> 24);
    a[4] += d * f8dec1(p.y & 0xFF); a[5] += d * f8dec1((p.y >> 8) & 0xFF);
    a[6] += d * f8dec1((p.y >> 16) & 0xFF); a[7] += d * f8dec1(p.y >> 24);
#endif
}

__device__ __forceinline__ void acc8(uint4 p, float* a) {
    a[0] += bflo(p.x); a[1] += bfhi(p.x);
    a[2] += bflo(p.y); a[3] += bfhi(p.y);
    a[4] += bflo(p.z); a[5] += bfhi(p.z);
    a[6] += bflo(p.w); a[7] += bfhi(p.w);
}
__device__ __forceinline__ uint4 pack8(const float* a) {
    uint4 r;
    r.x = (unsigned)f2bf(a[0]) | ((unsigned)f2bf(a[1]) << 16);
    r.y = (unsigned)f2bf(a[2]) | ((unsigned)f2bf(a[3]) << 16);
    r.z = (unsigned)f2bf(a[4]) | ((unsigned)f2bf(a[5]) << 16);
    r.w = (unsigned)f2bf(a[6]) | ((unsigned)f2bf(a[7]) << 16);
    return r;
}
__device__ __forceinline__ float sigmoidf_(float x) { return 1.f / (1.f + __expf(-x)); }
__device__ __forceinline__ float tanhf_(float x) { return 1.f - 2.f / (1.f + __expf(2.f * x)); }

__device__ __forceinline__ short8 ldfrag_f32(const float* p) {
    float4 a = *(const float4*)p;
    float4 b = *(const float4*)(p + 4);
    short8 r;
    r[0] = (short)f2bf(a.x); r[1] = (short)f2bf(a.y);
    r[2] = (short)f2bf(a.z); r[3] = (short)f2bf(a.w);
    r[4] = (short)f2bf(b.x); r[5] = (short)f2bf(b.y);
    r[6] = (short)f2bf(b.z); r[7] = (short)f2bf(b.w);
    return r;
}

// ---------------- fused: gemm1 (MFMA) || deg_out hist (LDS, packed u8) || partition ----
// Roles by blockIdx: [0,Gg)=gemm1; [Gg,Gg+NH)=deg_out hist; rest=partition chunks.
// NOTE (R4 lesson): same-stream dispatches serialize; this block-role fusion IS the
// overlap mechanism for the build phase. Do not split.
// NOTE (R6 lesson): no block-wide barrier after a variable-length per-thread phase.
// R8: xw1 stored as fp8 e4m3 (gates path) -> agg1 gather demand halves (410->205 MB).

__global__ __launch_bounds__(256) void k_fused(
    const float* __restrict__ x, const float* __restrict__ h, const float* __restrict__ Wg,
    const int* __restrict__ src, const int* __restrict__ dst, int E,
    int* __restrict__ bin_cur, unsigned* __restrict__ deg_part, unsigned* __restrict__ bins,
    unsigned char* __restrict__ xw1, int N, int NpadW, int NBINS, int Gg, int NH, int eps) {
    constexpr int NT = 8;                    // NOUT = 128
    __shared__ int sh[CHUNK + 1024];         // 68KB union: gemm Wswz | hist words | sort+aux
    int tid = threadIdx.x;
    int bid = blockIdx.x;
    if (bid >= Gg + NH) {
        // ---- partition role: counting-sort one chunk into coarse bins ----
        int* hist = &sh[CHUNK];
        int* pref = &sh[CHUNK + 256];
        int* offs = &sh[CHUNK + 512];
        int* base = &sh[CHUNK + 768];
        int* wsc  = &sh[CHUNK + 1016];
        int c = bid - Gg - NH;
        int e0 = c * CHUNK, e1 = min(E, e0 + CHUNK);
        int n = e1 - e0, n4 = n >> 2;
        for (int b = tid; b < NBINS; b += 256) hist[b] = 0;
        __syncthreads();
        const int4* d4 = (const int4*)(dst + e0);
        const int4* s4 = (const int4*)(src + e0);
        for (int i = tid; i < n4; i += 256) {
            int4 d = d4[i];
            atomicAdd(&hist[d.x >> PB], 1);
            atomicAdd(&hist[d.y >> PB], 1);
            atomicAdd(&hist[d.z >> PB], 1);
            atomicAdd(&hist[d.w >> PB], 1);
        }
        for (int e = e0 + (n4 << 2) + tid; e < e1; e += 256) atomicAdd(&hist[dst[e] >> PB], 1);
        __syncthreads();
        // wave-parallel exclusive scan over NBINS (<=256) entries
        int hv = (tid < NBINS) ? hist[tid] : 0;
        int val = hv;
        #pragma unroll
        for (int off = 1; off < 64; off <<= 1) {
            int u = __shfl_up(val, off);
            if ((tid & 63) >= off) val += u;
        }
        if ((tid & 63) == 63) wsc[tid >> 6] = val;
        __syncthreads();
        int wb = 0;
        #pragma unroll
        for (int w = 0; w < 4; w++) if (w < (tid >> 6)) wb += wsc[w];
        if (tid < NBINS) {
            int ex = wb + val - hv;
            pref[tid] = ex;
            offs[tid] = ex;
            if (hv) base[tid] = atomicAdd(&bin_cur[tid * BSTRIDE], hv);
        }
        __syncthreads();
        for (int i = tid; i < n4; i += 256) {
            int4 d = d4[i]; int4 sv = s4[i];
            int sl;
            sl = atomicAdd(&offs[d.x >> PB], 1);
            sh[sl] = (int)(((unsigned)(d.x & (PW - 1)) << 17) | (unsigned)sv.x);
            sl = atomicAdd(&offs[d.y >> PB], 1);
            sh[sl] = (int)(((unsigned)(d.y & (PW - 1)) << 17) | (unsigned)sv.y);
            sl = atomicAdd(&offs[d.z >> PB], 1);
            sh[sl] = (int)(((unsigned)(d.z & (PW - 1)) << 17) | (unsigned)sv.z);
            sl = atomicAdd(&offs[d.w >> PB], 1);
            sh[sl] = (int)(((unsigned)(d.w & (PW - 1)) << 17) | (unsigned)sv.w);
        }
        for (int e = e0 + (n4 << 2) + tid; e < e1; e += 256) {
            int d = dst[e];
            int sl = atomicAdd(&offs[d >> PB], 1);
            sh[sl] = (int)(((unsigned)(d & (PW - 1)) << 17) | (unsigned)src[e]);
        }
        __syncthreads();
        // wave-split write-out: wave w handles bins w, w+4, ...
        int wave = tid >> 6, lane = tid & 63;
        for (int b = wave; b < NBINS; b += 4) {
            int cnt = hist[b];
            if (!cnt) continue;
            int bs = base[b], pb = pref[b];
            int lim = min(cnt, BCAP - bs);          // overflow guard (P~0)
            unsigned* outp = &bins[(size_t)b * BCAP + bs];
            for (int j = lane; j < lim; j += 64) outp[j] = (unsigned)sh[pb + j];
        }
        return;
    }
    if (bid >= Gg) {
        // ---- deg_out hist role: node range r (65536 nodes, u8-packed), edge slice s ----
        int hb = bid - Gg;
        int r = hb / HS, s = hb % HS;
        int nbase = r << HBITS;
        unsigned* shw = (unsigned*)sh;
        for (int i = tid; i < WORDS; i += 256) shw[i] = 0u;
        __syncthreads();
        int e0 = s * eps, e1 = min(E, e0 + eps);
        int n = max(e1 - e0, 0), n4 = n >> 2;
        const int4* s4 = (const int4*)(src + e0);
        for (int i = tid; i < n4; i += 256) {
            int4 sv = s4[i];
            unsigned v;
            v = (unsigned)(sv.x - nbase);
            if (v < (unsigned)(1 << HBITS)) atomicAdd(&shw[v >> 2], 1u << ((v & 3) << 3));
            v = (unsigned)(sv.y - nbase);
            if (v < (unsigned)(1 << HBITS)) atomicAdd(&shw[v >> 2], 1u << ((v & 3) << 3));
            v = (unsigned)(sv.z - nbase);
            if (v < (unsigned)(1 << HBITS)) atomicAdd(&shw[v >> 2], 1u << ((v & 3) << 3));
            v = (unsigned)(sv.w - nbase);
            if (v < (unsigned)(1 << HBITS)) atomicAdd(&shw[v >> 2], 1u << ((v & 3) << 3));
        }
        for (int e = e0 + (n4 << 2) + tid; e < e1; e += 256) {
            unsigned v = (unsigned)(src[e] - nbase);
            if (v < (unsigned)(1 << HBITS)) atomicAdd(&shw[v >> 2], 1u << ((v & 3) << 3));
        }
        __syncthreads();
        unsigned* dp = deg_part + (size_t)s * NpadW + (nbase >> 2);
        for (int i = tid; i < WORDS; i += 256) dp[i] = shw[i];
        return;
    }
    // ---- gemm1 role: xw1 = [x|h]@Wg, UNSCALED (dno folded into agg1), fp8 output ----
    short* Wswz = (short*)sh;                // [ks][nt][lane][8] bf16
    for (int idx = tid; idx < 128 * 128; idx += 256) {
        int j = idx & 7, l = (idx >> 3) & 63, rest = idx >> 9;
        int nt = rest % NT, ks = rest / NT;
        int k = ks * 32 + ((l >> 4) << 3) + j;
        int n = nt * 16 + (l & 15);
        Wswz[idx] = (short)f2bf(Wg[k * 128 + n]);
    }
    __syncthreads();
    int wave = tid >> 6, lane = tid & 63;
    int ml = lane & 15, quad = lane >> 4;
    for (int mb = bid * 64; mb < N; mb += Gg * 64) {
        int row = mb + wave * 16 + ml;
        int rc = row < N ? row : N - 1;
        floatx4 acc[NT];
        #pragma unroll
        for (int nt = 0; nt < NT; nt++) acc[nt] = (floatx4){0.f, 0.f, 0.f, 0.f};
        #pragma unroll
        for (int ks = 0; ks < 4; ks++) {
            const float* basep = (ks < 2) ? x : h;
            int ko = (ks & 1) * 32 + quad * 8;
            short8 a = ldfrag_f32(&basep[(size_t)rc * 64 + ko]);
            #pragma unroll
            for (int nt = 0; nt < NT; nt++) {
                short8 b = *(const short8*)&Wswz[((ks * NT + nt) * 64 + lane) * 8];
                acc[nt] = __builtin_amdgcn_mfma_f32_16x16x32_bf16(a, b, acc[nt], 0, 0, 0);
            }
        }
        int r0 = mb + wave * 16 + quad * 4;
        #pragma unroll
        for (int nt = 0; nt < NT; nt++) {
            #pragma unroll
            for (int i = 0; i < 4; i++) {
                int gr = r0 + i;
                if (gr < N) xw1[(size_t)gr * 128 + nt * 16 + ml] = f8enc(acc[nt][i]);
            }
        }
    }
}

// ---------------- k_csr: fine CSR per bin (LDS sort, int4 I/O, shfl scan) || dno norm ----

__global__ __launch_bounds__(256) void k_csr(
    unsigned* __restrict__ bins, const int* __restrict__ bin_cur,
    const unsigned* __restrict__ deg_part, int* __restrict__ row_beg, int* __restrict__ deg_in,
    float* __restrict__ dni, float* __restrict__ dno, int N, int NpadW, int NBINS) {
    int tid = threadIdx.x;
    int bid = blockIdx.x;
    if (bid >= NBINS) {
        int i = (bid - NBINS) * 256 + tid;
        if (i < N) {
            int w = i >> 2, shf = (i & 3) << 3;
            int acc = 0;
            #pragma unroll 8
            for (int s = 0; s < HS; s++) acc += (int)((deg_part[(size_t)s * NpadW + w] >> shf) & 0xffu);
            dno[i] = rsqrtf(fmaxf((float)acc, 1.0f));
        }
        return;
    }
    __shared__ int eidx_s[BCAP];
    __shared__ int fh[PW], fp[PW], offs[PW];
    __shared__ int wsc2[4];
    int b = bid;
    int cnt = min(bin_cur[b * BSTRIDE], BCAP);
    unsigned* bp = &bins[(size_t)b * BCAP];
    int n4 = cnt >> 2;
    const uint4* bp4 = (const uint4*)bp;
    for (int i = tid; i < PW; i += 256) fh[i] = 0;
    __syncthreads();
    for (int i = tid; i < n4; i += 256) {
        uint4 v = bp4[i];
        atomicAdd(&fh[v.x >> 17], 1);
        atomicAdd(&fh[v.y >> 17], 1);
        atomicAdd(&fh[v.z >> 17], 1);
        atomicAdd(&fh[v.w >> 17], 1);
    }
    for (int j = (n4 << 2) + tid; j < cnt; j += 256) atomicAdd(&fh[bp[j] >> 17], 1);
    __syncthreads();
    // wave-parallel exclusive scan over PW=512 entries (2 per thread)
    {
        int a0 = fh[2 * tid], a1 = fh[2 * tid + 1];
        int ps = a0 + a1;
        int val = ps;
        #pragma unroll
        for (int off = 1; off < 64; off <<= 1) {
            int u = __shfl_up(val, off);
            if ((tid & 63) >= off) val += u;
        }
        if ((tid & 63) == 63) wsc2[tid >> 6] = val;
        __syncthreads();
        int wb = 0;
        #pragma unroll
        for (int w = 0; w < 4; w++) if (w < (tid >> 6)) wb += wsc2[w];
        int ex = wb + val - ps;
        fp[2 * tid] = ex; fp[2 * tid + 1] = ex + a0;
        offs[2 * tid] = ex; offs[2 * tid + 1] = ex + a0;
    }
    __syncthreads();
    for (int i = tid; i < n4; i += 256) {
        uint4 v = bp4[i];
        int sl;
        sl = atomicAdd(&offs[v.x >> 17], 1); eidx_s[sl] = (int)(v.x & 0x1FFFFu);
        sl = atomicAdd(&offs[v.y >> 17], 1); eidx_s[sl] = (int)(v.y & 0x1FFFFu);
        sl = atomicAdd(&offs[v.z >> 17], 1); eidx_s[sl] = (int)(v.z & 0x1FFFFu);
        sl = atomicAdd(&offs[v.w >> 17], 1); eidx_s[sl] = (int)(v.w & 0x1FFFFu);
    }
    for (int j = (n4 << 2) + tid; j < cnt; j += 256) {
        unsigned v = bp[j];
        int sl = atomicAdd(&offs[v >> 17], 1);
        eidx_s[sl] = (int)(v & 0x1FFFFu);
    }
    __syncthreads();
    uint4* bpw = (uint4*)bp;
    for (int i = tid; i < n4; i += 256) {
        uint4 o;
        o.x = (unsigned)eidx_s[4 * i];     o.y = (unsigned)eidx_s[4 * i + 1];
        o.z = (unsigned)eidx_s[4 * i + 2]; o.w = (unsigned)eidx_s[4 * i + 3];
        bpw[i] = o;
    }
    for (int j = (n4 << 2) + tid; j < cnt; j += 256) bp[j] = (unsigned)eidx_s[j];
    int nb = b << PB;
    for (int i = tid; i < PW; i += 256) {
        int node = nb + i;
        if (node < N) {
            row_beg[node] = b * BCAP + fp[i];
            int dg = fh[i];
            deg_in[node] = dg;
            dni[node] = rsqrtf(fmaxf((float)dg, 1.0f));
        }
    }
}

// ---------------- gemm2: xw2[n] = dno[n] * ([x[n] fp32, rhb[n] bf16] @ Wc) ----------------

__global__ __launch_bounds__(256) void k_gemm2(
    const float* __restrict__ x, const unsigned short* __restrict__ rhb,
    const float* __restrict__ Wc, const float* __restrict__ dno,
    unsigned short* __restrict__ xw2, int N) {
    constexpr int NT = 4;           // NOUT = 64
    __shared__ short Wswz[4 * NT * 64 * 8];  // 16 KB
    int tid = threadIdx.x;
    for (int idx = tid; idx < 128 * 64; idx += 256) {
        int j = idx & 7, l = (idx >> 3) & 63, rest = idx >> 9;
        int nt = rest % NT, ks = rest / NT;
        int k = ks * 32 + ((l >> 4) << 3) + j;
        int n = nt * 16 + (l & 15);
        Wswz[idx] = (short)f2bf(Wc[k * 64 + n]);
    }
    __syncthreads();
    int wave = tid >> 6, lane = tid & 63;
    int ml = lane & 15, quad = lane >> 4;
    for (int mb = blockIdx.x * 64; mb < N; mb += gridDim.x * 64) {
        int row = mb + wave * 16 + ml;
        int rc = row < N ? row : N - 1;
        floatx4 acc[NT];
        #pragma unroll
        for (int nt = 0; nt < NT; nt++) acc[nt] = (floatx4){0.f, 0.f, 0.f, 0.f};
        #pragma unroll
        for (int ks = 0; ks < 4; ks++) {
            int ko = (ks & 1) * 32 + quad * 8;
            short8 a;
            if (ks < 2) a = ldfrag_f32(&x[(size_t)rc * 64 + ko]);
            else        a = *(const short8*)&rhb[(size_t)rc * 64 + ko];
            #pragma unroll
            for (int nt = 0; nt < NT; nt++) {
                short8 b = *(const short8*)&Wswz[((ks * NT + nt) * 64 + lane) * 8];
                acc[nt] = __builtin_amdgcn_mfma_f32_16x16x32_bf16(a, b, acc[nt], 0, 0, 0);
            }
        }
        int r0 = mb + wave * 16 + quad * 4;
        float sv[4];
        #pragma unroll
        for (int i = 0; i < 4; i++) sv[i] = dno[min(r0 + i, N - 1)];
        #pragma unroll
        for (int nt = 0; nt < NT; nt++) {
            #pragma unroll
            for (int i = 0; i < 4; i++) {
                int gr = r0 + i;
                if (gr < N) xw2[(size_t)gr * 64 + nt * 16 + ml] = f2bf(acc[nt][i] * sv[i]);
            }
        }
    }
}

// ---------------- agg1 (fused gates): 16 lanes/node, fp8 gather, per-edge dno fma ----------
// Barrier-free: threads retire independently (R6 lesson — no skew coupling).

__global__ __launch_bounds__(256) void k_agg1(
    const unsigned char* __restrict__ xw1, const int* __restrict__ row_beg,
    const int* __restrict__ deg_in, const unsigned* __restrict__ srt,
    const float* __restrict__ dno, const float* __restrict__ dni,
    const float* __restrict__ bg, const float* __restrict__ h,
    float* __restrict__ ug, unsigned short* __restrict__ rh, int N) {
    int tx = threadIdx.x & 15;
    int ty = threadIdx.x >> 4;  // 16 nodes per block
    for (int v = blockIdx.x * 16 + ty; v < N; v += gridDim.x * 16) {
        int beg = row_beg[v];
        int end = beg + deg_in[v];
        float a[8] = {};
        int e = beg;
        for (; e + 3 < end; e += 4) {
            int s0 = srt[e], s1 = srt[e + 1], s2 = srt[e + 2], s3 = srt[e + 3];
            float d0 = dno[s0], d1 = dno[s1], d2 = dno[s2], d3 = dno[s3];
            uint2 p0 = *(const uint2*)&xw1[(size_t)s0 * 128 + tx * 8];
            uint2 p1 = *(const uint2*)&xw1[(size_t)s1 * 128 + tx * 8];
            uint2 p2 = *(const uint2*)&xw1[(size_t)s2 * 128 + tx * 8];
            uint2 p3 = *(const uint2*)&xw1[(size_t)s3 * 128 + tx * 8];
            fma8f8(p0, d0, a); fma8f8(p1, d1, a); fma8f8(p2, d2, a); fma8f8(p3, d3, a);
        }
        for (; e < end; e++) {
            int s = srt[e];
            float d = dno[s];
            uint2 p = *(const uint2*)&xw1[(size_t)s * 128 + tx * 8];
            fma8f8(p, d, a);
        }
        float sc = dni[v];
        float4 b0 = *(const float4*)&bg[tx * 8];
        float4 b1 = *(const float4*)&bg[tx * 8 + 4];
        float g[8];
        g[0] = sigmoidf_(a[0] * sc + b0.x); g[1] = sigmoidf_(a[1] * sc + b0.y);
        g[2] = sigmoidf_(a[2] * sc + b0.z); g[3] = sigmoidf_(a[3] * sc + b0.w);
        g[4] = sigmoidf_(a[4] * sc + b1.x); g[5] = sigmoidf_(a[5] * sc + b1.y);
        g[6] = sigmoidf_(a[6] * sc + b1.z); g[7] = sigmoidf_(a[7] * sc + b1.w);
        if (tx < 8) {  // reset gate cols tx*8..+7 -> rh = r*h (bf16)
            float4 h0 = *(const float4*)&h[(size_t)v * 64 + tx * 8];
            float4 h1 = *(const float4*)&h[(size_t)v * 64 + tx * 8 + 4];
            float r[8] = {g[0] * h0.x, g[1] * h0.y, g[2] * h0.z, g[3] * h0.w,
                          g[4] * h1.x, g[5] * h1.y, g[6] * h1.z, g[7] * h1.w};
            *(uint4*)&rh[(size_t)v * 64 + tx * 8] = pack8(r);
        } else {       // update gate -> ug (fp32)
            int c = (tx - 8) * 8;
            float4 o0 = {g[0], g[1], g[2], g[3]};
            float4 o1 = {g[4], g[5], g[6], g[7]};
            *(float4*)&ug[(size_t)v * 64 + c] = o0;
            *(float4*)&ug[(size_t)v * 64 + c + 4] = o1;
        }
    }
}

// ---------------- agg2 (fused GRU blend): 8 lanes/node, bf16 gather ----------------

__global__ __launch_bounds__(256) void k_agg2(
    const unsigned short* __restrict__ xw2, const int* __restrict__ row_beg,
    const int* __restrict__ deg_in, const unsigned* __restrict__ srt,
    const float* __restrict__ dni, const float* __restrict__ bc,
    const float* __restrict__ h, const float* __restrict__ ug, float* __restrict__ out, int N) {
    int tx = threadIdx.x & 7;
    int ty = threadIdx.x >> 3;  // 32 nodes per block
    for (int v = blockIdx.x * 32 + ty; v < N; v += gridDim.x * 32) {
        int beg = row_beg[v];
        int end = beg + deg_in[v];
        float a[8] = {};
        int e = beg;
        for (; e + 3 < end; e += 4) {
            int s0 = srt[e], s1 = srt[e + 1], s2 = srt[e + 2], s3 = srt[e + 3];
            uint4 p0 = *(const uint4*)&xw2[(size_t)s0 * 64 + tx * 8];
            uint4 p1 = *(const uint4*)&xw2[(size_t)s1 * 64 + tx * 8];
            uint4 p2 = *(const uint4*)&xw2[(size_t)s2 * 64 + tx * 8];
            uint4 p3 = *(const uint4*)&xw2[(size_t)s3 * 64 + tx * 8];
            acc8(p0, a); acc8(p1, a); acc8(p2, a); acc8(p3, a);
        }
        for (; e < end; e++) {
            int s = srt[e];
            uint4 p = *(const uint4*)&xw2[(size_t)s * 64 + tx * 8];
            acc8(p, a);
        }
        float sc = dni[v];
        float4 b0 = *(const float4*)&bc[tx * 8];
        float4 b1 = *(const float4*)&bc[tx * 8 + 4];
        float c[8];
        c[0] = tanhf_(a[0] * sc + b0.x); c[1] = tanhf_(a[1] * sc + b0.y);
        c[2] = tanhf_(a[2] * sc + b0.z); c[3] = tanhf_(a[3] * sc + b0.w);
        c[4] = tanhf_(a[4] * sc + b1.x); c[5] = tanhf_(a[5] * sc + b1.y);
        c[6] = tanhf_(a[6] * sc + b1.z); c[7] = tanhf_(a[7] * sc + b1.w);
        float4 u0 = *(const float4*)&ug[(size_t)v * 64 + tx * 8];
        float4 u1 = *(const float4*)&ug[(size_t)v * 64 + tx * 8 + 4];
        float4 h0 = *(const float4*)&h[(size_t)v * 64 + tx * 8];
        float4 h1 = *(const float4*)&h[(size_t)v * 64 + tx * 8 + 4];
        float4 o0 = {u0.x * h0.x + (1.f - u0.x) * c[0], u0.y * h0.y + (1.f - u0.y) * c[1],
                     u0.z * h0.z + (1.f - u0.z) * c[2], u0.w * h0.w + (1.f - u0.w) * c[3]};
        float4 o1 = {u1.x * h1.x + (1.f - u1.x) * c[4], u1.y * h1.y + (1.f - u1.y) * c[5],
                     u1.z * h1.z + (1.f - u1.z) * c[6], u1.w * h1.w + (1.f - u1.w) * c[7]};
        *(float4*)&out[(size_t)v * 64 + tx * 8] = o0;
        *(float4*)&out[(size_t)v * 64 + tx * 8 + 4] = o1;
    }
}

// ---------------- launch ----------------

extern "C" void kernel_launch(void* const* d_in, const int* in_sizes, int n_in,
                              void* d_out, int out_size, void* d_ws, size_t ws_size,
                              hipStream_t stream) {
    const float* x  = (const float*)d_in[0];
    const float* h  = (const float*)d_in[1];
    const int*   src = (const int*)d_in[2];
    const int*   dst = (const int*)d_in[3];
    const float* Wg = (const float*)d_in[4];
    const float* bg = (const float*)d_in[5];
    const float* Wc = (const float*)d_in[6];
    const float* bc = (const float*)d_in[7];
    float* out = (float*)d_out;

    const int N = in_sizes[0] / 64;
    const int E = in_sizes[2];
    const int NBINS = (N + PW - 1) >> PB;          // coarse bins (512 nodes)
    const int NCH = (E + CHUNK - 1) / CHUNK;       // partition chunks
    const int NR = (N + (1 << HBITS) - 1) >> HBITS; // deg_out hist node ranges (65536 each)
    const int NpadW = NR << (HBITS - 2);           // words per slice (u8-packed)
    const int NH = NR * HS;                        // hist blocks
    const int eps = (((E + HS - 1) / HS) + 3) & ~3; // slice size, 4-aligned for int4

    char* ws = (char*)d_ws;
    size_t off = 0;
    auto alloc = [&](size_t bytes) -> char* {
        char* p = ws + off;
        off = (off + bytes + 255) & ~(size_t)255;
        return p;
    };
    int* bin_cur = (int*)alloc((size_t)NBINS * BSTRIDE * 4);   // padded: 1 counter / 64B
    int* row_beg = (int*)alloc((size_t)N * 4);
    int* deg_in  = (int*)alloc((size_t)N * 4);
    float* dno = (float*)alloc((size_t)N * 4);
    float* dni = (float*)alloc((size_t)N * 4);
    unsigned* bins = (unsigned*)alloc((size_t)NBINS * BCAP * 4);
    unsigned short* rhb = (unsigned short*)alloc((size_t)N * 64 * 2);
    unsigned char* xw1 = (unsigned char*)alloc((size_t)N * 128);   // fp8 e4m3
    float* ug = (float*)alloc((size_t)N * 64 * 4);
    unsigned short* xw2 = (unsigned short*)xw1; // xw1 (N*128 B) dead after agg1; xw2 needs
                                                // N*64*2 B = same size. reuse.
    unsigned* deg_part = (unsigned*)ug; // HS*NpadW*4 = 4.2MB <= ug's 25.6MB;
                                        // dead before agg1 writes ug

    const int Gg = 256;                 // gemm1 blocks (dispatch first, persist)

    hipMemsetAsync(bin_cur, 0, (size_t)NBINS * BSTRIDE * 4, stream);
    k_fused<<<Gg + NH + NCH, 256, 0, stream>>>(x, h, Wg, src, dst, E,
                                               bin_cur, deg_part, bins, xw1,
                                               N, NpadW, NBINS, Gg, NH, eps);
    k_csr<<<NBINS + (N + 255) / 256, 256, 0, stream>>>(bins, bin_cur, deg_part,
                                                       row_beg, deg_in, dni, dno,
                                                       N, NpadW, NBINS);
    k_agg1<<<(N + 15) / 16, 256, 0, stream>>>(xw1, row_beg, deg_in, bins,
                                              dno, dni, bg, h, ug, rhb, N);
    k_gemm2<<<512, 256, 0, stream>>>(x, rhb, Wc, dno, xw2, N);
    k_agg2<<<(N + 31) / 32, 256, 0, stream>>>(xw2, row_beg, deg_in, bins,
                                              dni, bc, h, ug, out, N);
}